// Round 1
// baseline (2076.202 us; speedup 1.0000x reference)
//
#include <hip/hip_runtime.h>
#include <hip/hip_bf16.h>

// Problem constants
// B=2, S=1024, L=1024, DIM_Q=2048, H=16, K=128, D_C=512, D_CQ=1536, R=64

__device__ __forceinline__ float4 load4(const float* p){ return *(const float4*)p; }
__device__ __forceinline__ float4 load4(const __hip_bfloat16* p){
  ushort4 u = *(const ushort4*)p;
  return make_float4(__uint_as_float((unsigned)u.x << 16),
                     __uint_as_float((unsigned)u.y << 16),
                     __uint_as_float((unsigned)u.z << 16),
                     __uint_as_float((unsigned)u.w << 16));
}
__device__ __forceinline__ void storeC(float* p, float v){ *p = v; }
__device__ __forceinline__ void storeC(__hip_bfloat16* p, float v){ *p = __float2bfloat16(v); }
__device__ __forceinline__ unsigned short f2bs(float v){
  __hip_bfloat16 b = __float2bfloat16(v);
  return *reinterpret_cast<unsigned short*>(&b);
}

// ---------------------------------------------------------------------------
// sin/cos tables, repeat_interleave(2) layout.  q-table: [1024][1536], k: [1024][512]
__global__ __launch_bounds__(256) void build_tables(
    float* __restrict__ sinq, float* __restrict__ cosq,
    float* __restrict__ sink, float* __restrict__ cosk)
{
  int idx = blockIdx.x*256 + threadIdx.x;
  if (idx < 1024*768){
    int s = idx / 768, j = idx % 768;
    float f = (float)s * powf(10000.f, (-2.f*j)/1536.f);
    float sv = sinf(f), cv = cosf(f);
    int base = s*1536 + 2*j;
    sinq[base] = sv; sinq[base+1] = sv;
    cosq[base] = cv; cosq[base+1] = cv;
  } else {
    int k = idx - 1024*768;           // < 1024*256
    int l = k / 256, j = k % 256;
    float f = (float)l * powf(10000.f, (-2.f*j)/512.f);
    float sv = sinf(f), cv = cosf(f);
    int base = l*512 + 2*j;
    sink[base] = sv; sink[base+1] = sv;
    cosk[base] = cv; cosk[base+1] = cv;
  }
}

// ---------------------------------------------------------------------------
// Generic batched GEMM: C[m,n] = sum_k A[m,k]*B[.,.]
//   A: row-major [M,K] (k-contiguous), element type TA (float or bf16)
//   BT=true : B[n*ldb + k]  (NT, k-contiguous rows)
//   BT=false: B[k*ldb + n]  (NN, n-contiguous rows)
// Tile: 64(m) x BN(n) x 16(k); 256 threads; microtile 4 x (BN/16).
// Batch z -> (bb=z/Hb, hh=z%Hb); per-operand element offsets.
template<typename TA, typename TC, bool BT, int BN>
__global__ __launch_bounds__(256) void gemm64(
    const TA* __restrict__ A, const float* __restrict__ B, TC* __restrict__ C,
    int Kd, int lda, int ldb, int ldc, int Hb,
    long sAb, long sAh, long sBb, long sBh, long sCb, long sCh)
{
  constexpr int NW = BN/16;
  const int z = blockIdx.z;
  const int bb = z / Hb, hh = z % Hb;
  const TA* Ap = A + (long)bb*sAb + (long)hh*sAh;
  const float* Bp = B + (long)bb*sBb + (long)hh*sBh;
  TC* Cp = C + (long)bb*sCb + (long)hh*sCh;
  const int m0 = blockIdx.x*64, n0 = blockIdx.y*BN;

  __shared__ float As[16][68];
  __shared__ float Bs[16][BN+4];

  const int t = threadIdx.x;
  const int tm = t >> 4, tn = t & 15;
  float acc[4][NW];
  #pragma unroll
  for (int i = 0; i < 4; ++i)
    #pragma unroll
    for (int j = 0; j < NW; ++j) acc[i][j] = 0.f;

  const int am = t >> 2, ak = (t & 3)*4;

  for (int k0 = 0; k0 < Kd; k0 += 16){
    // stage A: 64x16
    {
      float4 av = load4(Ap + (long)(m0+am)*lda + k0 + ak);
      As[ak+0][am] = av.x; As[ak+1][am] = av.y;
      As[ak+2][am] = av.z; As[ak+3][am] = av.w;
    }
    // stage B: BNx16
    #pragma unroll
    for (int e = 0; e < BN/64; ++e){
      int idx = t + e*256;
      if constexpr (BT){
        int n = idx >> 2, kq = (idx & 3)*4;
        float4 bv = load4(Bp + (long)(n0+n)*ldb + k0 + kq);
        Bs[kq+0][n] = bv.x; Bs[kq+1][n] = bv.y;
        Bs[kq+2][n] = bv.z; Bs[kq+3][n] = bv.w;
      } else {
        constexpr int NQ = BN/4;
        int kk = idx / NQ, nq = (idx % NQ)*4;
        float4 bv = load4(Bp + (long)(k0+kk)*ldb + n0 + nq);
        *(float4*)&Bs[kk][nq] = bv;
      }
    }
    __syncthreads();
    #pragma unroll
    for (int k = 0; k < 16; ++k){
      float4 a4 = *(const float4*)&As[k][tm*4];
      float bv[NW];
      #pragma unroll
      for (int j = 0; j < NW; j += 4){
        float4 b4 = *(const float4*)&Bs[k][tn*NW + j];
        bv[j] = b4.x; bv[j+1] = b4.y; bv[j+2] = b4.z; bv[j+3] = b4.w;
      }
      #pragma unroll
      for (int j = 0; j < NW; ++j){
        acc[0][j] += a4.x*bv[j];
        acc[1][j] += a4.y*bv[j];
        acc[2][j] += a4.z*bv[j];
        acc[3][j] += a4.w*bv[j];
      }
    }
    __syncthreads();
  }
  #pragma unroll
  for (int i = 0; i < 4; ++i){
    long roff = (long)(m0 + tm*4 + i)*ldc + n0 + tn*NW;
    #pragma unroll
    for (int j = 0; j < NW; ++j) storeC(Cp + roff + j, acc[i][j]);
  }
}

// ---------------------------------------------------------------------------
// RoPE on q_big (bf16, in place).  Layout [b,s][h*1536+q]; pairs (q, q+768).
__global__ __launch_bounds__(256) void rope_q_kernel(
    __hip_bfloat16* __restrict__ qb,
    const float* __restrict__ sq, const float* __restrict__ cq)
{
  int idx = blockIdx.x*256 + threadIdx.x;   // < 2*1024*16*768
  int row = idx / 768;
  int q = idx - row*768;
  int s = (row >> 4) & 1023;                // row = (b*1024+s)*16 + h
  long base = (long)row*1536;
  float xl = __bfloat162float(qb[base+q]);
  float xh = __bfloat162float(qb[base+q+768]);
  int tb = s*1536 + q;
  float yl = xl*cq[tb]     - xh*sq[tb];
  float yh = xh*cq[tb+768] + xl*sq[tb+768];
  qb[base+q]     = __float2bfloat16(yl);
  qb[base+q+768] = __float2bfloat16(yh);
}

// RoPE on kv_c -> kv_r (fp32).  [b,l,512]; pairs (d, d+256).
__global__ __launch_bounds__(256) void rope_k_kernel(
    const float* __restrict__ kc,
    const float* __restrict__ sk, const float* __restrict__ ck,
    float* __restrict__ kvr)
{
  int idx = blockIdx.x*256 + threadIdx.x;   // < 2*1024*256
  int row = idx >> 8;
  int d = idx & 255;
  int l = row & 1023;
  long base = (long)row*512;
  float xl = kc[base+d], xh = kc[base+d+256];
  int tb = l*512 + d;
  kvr[base+d]     = xl*ck[tb]     - xh*sk[tb];
  kvr[base+d+256] = xh*ck[tb+256] + xl*sk[tb+256];
}

// ---------------------------------------------------------------------------
// Flash attention: per WG (b, h, 32 q-rows).  K/V shared across heads (V=kv_r).
// Q,K tiles [32][64] LDS; V staged in 2 chunks [32][256]; online softmax.
// Thread map: si = t>>3 (q-row), dg = t&7.  O ownership: d = c*256 + j4*32 + dg*4 + w.
__global__ __launch_bounds__(256) void flash_attn(
    const float* __restrict__ qr, const float* __restrict__ kr,
    const float* __restrict__ kvr, __hip_bfloat16* __restrict__ ctx)
{
  const int b = blockIdx.z, h = blockIdx.y, s0 = blockIdx.x*32;
  const int t = threadIdx.x;
  __shared__ float Qs[32][68];
  __shared__ float Ks[32][68];
  __shared__ float Vs[32][260];
  __shared__ float Ss[32][36];
  __shared__ float mi[32], li[32], alp[32];

  const float* qbase = qr + (((long)(b*16+h))*1024 + s0)*64;
  const float* kbase = kr + ((long)(b*16+h))*65536;
  const float* vbase = kvr + (long)b*524288;

  #pragma unroll
  for (int e = 0; e < 2; ++e){
    int f = t + e*256;
    int row = f >> 4, col = (f & 15)*4;
    *(float4*)&Qs[row][col] = *(const float4*)(qbase + (long)row*64 + col);
  }
  if (t < 32){ mi[t] = -3e38f; li[t] = 0.f; }

  float acc[2][32];
  #pragma unroll
  for (int c = 0; c < 2; ++c)
    #pragma unroll
    for (int j = 0; j < 32; ++j) acc[c][j] = 0.f;

  const int si = t >> 3, dg = t & 7;

  for (int l0 = 0; l0 < 1024; l0 += 32){
    #pragma unroll
    for (int e = 0; e < 2; ++e){
      int f = t + e*256;
      int row = f >> 4, col = (f & 15)*4;
      *(float4*)&Ks[row][col] = *(const float4*)(kbase + (long)(l0+row)*64 + col);
    }
    __syncthreads();
    // scores S[si][dg*4 .. +3]
    {
      float sc0=0.f, sc1=0.f, sc2=0.f, sc3=0.f;
      #pragma unroll
      for (int r4 = 0; r4 < 16; ++r4){
        float4 q4 = *(const float4*)&Qs[si][r4*4];
        float4 k0v = *(const float4*)&Ks[dg*4+0][r4*4];
        float4 k1v = *(const float4*)&Ks[dg*4+1][r4*4];
        float4 k2v = *(const float4*)&Ks[dg*4+2][r4*4];
        float4 k3v = *(const float4*)&Ks[dg*4+3][r4*4];
        sc0 += q4.x*k0v.x + q4.y*k0v.y + q4.z*k0v.z + q4.w*k0v.w;
        sc1 += q4.x*k1v.x + q4.y*k1v.y + q4.z*k1v.z + q4.w*k1v.w;
        sc2 += q4.x*k2v.x + q4.y*k2v.y + q4.z*k2v.z + q4.w*k2v.w;
        sc3 += q4.x*k3v.x + q4.y*k3v.y + q4.z*k3v.z + q4.w*k3v.w;
      }
      Ss[si][dg*4+0] = sc0; Ss[si][dg*4+1] = sc1;
      Ss[si][dg*4+2] = sc2; Ss[si][dg*4+3] = sc3;
    }
    __syncthreads();
    if (t < 32){
      float mold = mi[t], mx = mold;
      for (int l = 0; l < 32; ++l) mx = fmaxf(mx, Ss[t][l]);
      float a = __expf(mold - mx);
      float sum = 0.f;
      for (int l = 0; l < 32; ++l){
        float p = __expf(Ss[t][l] - mx);
        Ss[t][l] = p; sum += p;
      }
      li[t] = li[t]*a + sum; mi[t] = mx; alp[t] = a;
    }
    __syncthreads();
    #pragma unroll
    for (int c = 0; c < 2; ++c){
      #pragma unroll
      for (int e = 0; e < 8; ++e){
        int row = (t >> 6)*8 + e;
        int col = (t & 63)*4;
        *(float4*)&Vs[row][col] = *(const float4*)(vbase + (long)(l0+row)*512 + c*256 + col);
      }
      __syncthreads();
      float a = alp[si];
      #pragma unroll
      for (int j = 0; j < 32; ++j) acc[c][j] *= a;
      #pragma unroll 4
      for (int l = 0; l < 32; ++l){
        float p = Ss[si][l];
        #pragma unroll
        for (int j4 = 0; j4 < 8; ++j4){
          float4 v = *(const float4*)&Vs[l][j4*32 + dg*4];
          acc[c][j4*4+0] += p*v.x;
          acc[c][j4*4+1] += p*v.y;
          acc[c][j4*4+2] += p*v.z;
          acc[c][j4*4+3] += p*v.w;
        }
      }
      __syncthreads();
    }
  }
  float inv = 1.f / li[si];
  unsigned short* cp = (unsigned short*)ctx + (((long)(b*16+h))*1024 + s0 + si)*512;
  #pragma unroll
  for (int c = 0; c < 2; ++c)
    #pragma unroll
    for (int j4 = 0; j4 < 8; ++j4){
      ushort4 u;
      u.x = f2bs(acc[c][j4*4+0]*inv);
      u.y = f2bs(acc[c][j4*4+1]*inv);
      u.z = f2bs(acc[c][j4*4+2]*inv);
      u.w = f2bs(acc[c][j4*4+3]*inv);
      *(ushort4*)(cp + c*256 + j4*32 + dg*4) = u;
    }
}

// ---------------------------------------------------------------------------
extern "C" void kernel_launch(void* const* d_in, const int* in_sizes, int n_in,
                              void* d_out, int out_size, void* d_ws, size_t ws_size,
                              hipStream_t stream)
{
  const float* hidden_q = (const float*)d_in[0];   // [2,1024,2048]
  const float* kv_c     = (const float*)d_in[1];   // [2,1024,512]
  const float* Wq       = (const float*)d_in[2];   // [2048,2048]
  const float* w_kc_q   = (const float*)d_in[3];   // [16,128,1536]
  const float* w_kc_kv  = (const float*)d_in[4];   // [16,128,512]
  const float* W_qr     = (const float*)d_in[5];   // [16,1536,64]
  const float* W_kr     = (const float*)d_in[6];   // [16,512,64]
  const float* Wo       = (const float*)d_in[7];   // [2048,2048]
  float* out = (float*)d_out;

  char* wsb = (char*)d_ws;
  size_t off = 0;
  auto take = [&](size_t bytes)->void*{
    void* p = wsb + off; off += (bytes + 255) & ~(size_t)255; return p;
  };
  float* q_r   = (float*)take(2097152ull*4);   // [B,H,S,64]
  float* k_r   = (float*)take(2097152ull*4);   // [B,H,L,64]
  float* kv_r  = (float*)take(1048576ull*4);   // [B,L,512]
  float* sink  = (float*)take(524288ull*4);
  float* cosk  = (float*)take(524288ull*4);
  float* sinq  = (float*)take(1572864ull*4);
  float* cosq  = (float*)take(1572864ull*4);
  float* q_hk  = (float*)take(4194304ull*4);   // [B*S, H*128]
  char*  bigr  = (char*)take(100663296ull);    // q_big bf16 region (aliased later)
  __hip_bfloat16* q_big = (__hip_bfloat16*)bigr;           // [B,S][H*1536]
  __hip_bfloat16* ctx_c = (__hip_bfloat16*)bigr;           // [B,H,S,512] (after q_big dead)
  float* ctx_lat = (float*)(bigr + 33554432);              // [B*S, H*128]

  // 1) tables
  build_tables<<<4096, 256, 0, stream>>>(sinq, cosq, sink, cosk);

  // 2) q_hk = hidden_q @ Wq^T   (M=2048,N=2048,K=2048)
  gemm64<float,float,true,128><<<dim3(32,16,1),256,0,stream>>>(
      hidden_q, Wq, q_hk, 2048, 2048,2048,2048, 1, 0,0, 0,0, 0,0);

  // 3) q_big[b,s][h*1536+q] = q_hk[b,s][h*128+k] @ w_kc_q[h][k][q]  (per (b,h): M=1024,N=1536,K=128)
  gemm64<float,__hip_bfloat16,false,128><<<dim3(16,12,32),256,0,stream>>>(
      q_hk, w_kc_q, q_big, 128, 2048,1536,24576, 16,
      2097152,128, 0,196608, 25165824,1536);

  // 4) RoPE q_big in place
  rope_q_kernel<<<98304, 256, 0, stream>>>(q_big, sinq, cosq);

  // 5) q_r[b,h,s,r] = q_big @ W_qr[h]  (per (b,h): M=1024,N=64,K=1536)
  gemm64<__hip_bfloat16,float,false,64><<<dim3(16,1,32),256,0,stream>>>(
      q_big, W_qr, q_r, 1536, 24576,64,64, 16,
      25165824,1536, 0,98304, 1048576,65536);

  // 6) kv_r = RoPE(kv_c)
  rope_k_kernel<<<2048, 256, 0, stream>>>(kv_c, sink, cosk, kv_r);

  // 7) k_r[b,h,l,r] = kv_r[b] @ W_kr[h]  (per (b,h): M=1024,N=64,K=512)
  gemm64<float,float,false,64><<<dim3(16,1,32),256,0,stream>>>(
      kv_r, W_kr, k_r, 512, 512,64,64, 16,
      524288,0, 0,32768, 1048576,65536);

  // 8) flash attention -> ctx_c[b,h,s,512] (bf16)
  flash_attn<<<dim3(32,16,2),256,0,stream>>>(q_r, k_r, kv_r, ctx_c);

  // 9) ctx_lat[b,s][h*128+k] = ctx_c[b,h,s,:] @ w_kc_kv[h][k][:]^T  (per (b,h): M=1024,N=128,K=512)
  gemm64<__hip_bfloat16,float,true,128><<<dim3(16,1,32),256,0,stream>>>(
      ctx_c, w_kc_kv, ctx_lat, 512, 512,512,2048, 16,
      8388608,524288, 0,65536, 2097152,128);

  // 10) out = ctx_lat @ Wo^T  (M=2048,N=2048,K=2048)
  gemm64<float,float,true,128><<<dim3(32,16,1),256,0,stream>>>(
      ctx_lat, Wo, out, 2048, 2048,2048,2048, 1, 0,0, 0,0, 0,0);
}

// Round 2
// 1292.386 us; speedup vs baseline: 1.6065x; 1.6065x over previous
//
#include <hip/hip_runtime.h>
#include <hip/hip_bf16.h>

// Problem constants
// B=2, S=1024, L=1024, DIM_Q=2048, H=16, K=128, D_C=512, D_CQ=1536, R=64

__device__ __forceinline__ float4 load4(const float* p){ return *(const float4*)p; }
__device__ __forceinline__ float4 load4(const __hip_bfloat16* p){
  ushort4 u = *(const ushort4*)p;
  return make_float4(__uint_as_float((unsigned)u.x << 16),
                     __uint_as_float((unsigned)u.y << 16),
                     __uint_as_float((unsigned)u.z << 16),
                     __uint_as_float((unsigned)u.w << 16));
}
__device__ __forceinline__ void storeC(float* p, float v){ *p = v; }
__device__ __forceinline__ void storeC(__hip_bfloat16* p, float v){ *p = __float2bfloat16(v); }

// ---------------------------------------------------------------------------
// sin/cos tables, repeat_interleave(2) layout.  q-table: [1024][1536], k: [1024][512]
__global__ __launch_bounds__(256) void build_tables(
    float* __restrict__ sinq, float* __restrict__ cosq,
    float* __restrict__ sink, float* __restrict__ cosk)
{
  int idx = blockIdx.x*256 + threadIdx.x;
  if (idx < 1024*768){
    int s = idx / 768, j = idx % 768;
    float f = (float)s * powf(10000.f, (-2.f*j)/1536.f);
    float sv = sinf(f), cv = cosf(f);
    int base = s*1536 + 2*j;
    sinq[base] = sv; sinq[base+1] = sv;
    cosq[base] = cv; cosq[base+1] = cv;
  } else {
    int k = idx - 1024*768;           // < 1024*256
    int l = k / 256, j = k % 256;
    float f = (float)l * powf(10000.f, (-2.f*j)/512.f);
    float sv = sinf(f), cv = cosf(f);
    int base = l*512 + 2*j;
    sink[base] = sv; sink[base+1] = sv;
    cosk[base] = cv; cosk[base+1] = cv;
  }
}

// ---------------------------------------------------------------------------
// Generic batched GEMM: C[m,n] = sum_k A[m,k]*B[.,.]
//   A: row-major [M,K] (k-contiguous), element type TA (float or bf16)
//   BT=true : B[n*ldb + k]  (NT, k-contiguous rows)
//   BT=false: B[k*ldb + n]  (NN, n-contiguous rows)
// Tile: 64(m) x BN(n) x 16(k); 256 threads; microtile 4 x (BN/16).
template<typename TA, typename TC, bool BT, int BN>
__global__ __launch_bounds__(256) void gemm64(
    const TA* __restrict__ A, const float* __restrict__ B, TC* __restrict__ C,
    int Kd, int lda, int ldb, int ldc, int Hb,
    long sAb, long sAh, long sBb, long sBh, long sCb, long sCh)
{
  constexpr int NW = BN/16;
  const int z = blockIdx.z;
  const int bb = z / Hb, hh = z % Hb;
  const TA* Ap = A + (long)bb*sAb + (long)hh*sAh;
  const float* Bp = B + (long)bb*sBb + (long)hh*sBh;
  TC* Cp = C + (long)bb*sCb + (long)hh*sCh;
  const int m0 = blockIdx.x*64, n0 = blockIdx.y*BN;

  __shared__ float As[16][68];
  __shared__ float Bs[16][BN+4];

  const int t = threadIdx.x;
  const int tm = t >> 4, tn = t & 15;
  float acc[4][NW];
  #pragma unroll
  for (int i = 0; i < 4; ++i)
    #pragma unroll
    for (int j = 0; j < NW; ++j) acc[i][j] = 0.f;

  const int am = t >> 2, ak = (t & 3)*4;

  for (int k0 = 0; k0 < Kd; k0 += 16){
    {
      float4 av = load4(Ap + (long)(m0+am)*lda + k0 + ak);
      As[ak+0][am] = av.x; As[ak+1][am] = av.y;
      As[ak+2][am] = av.z; As[ak+3][am] = av.w;
    }
    #pragma unroll
    for (int e = 0; e < BN/64; ++e){
      int idx = t + e*256;
      if constexpr (BT){
        int n = idx >> 2, kq = (idx & 3)*4;
        float4 bv = load4(Bp + (long)(n0+n)*ldb + k0 + kq);
        Bs[kq+0][n] = bv.x; Bs[kq+1][n] = bv.y;
        Bs[kq+2][n] = bv.z; Bs[kq+3][n] = bv.w;
      } else {
        constexpr int NQ = BN/4;
        int kk = idx / NQ, nq = (idx % NQ)*4;
        float4 bv = load4(Bp + (long)(k0+kk)*ldb + n0 + nq);
        *(float4*)&Bs[kk][nq] = bv;
      }
    }
    __syncthreads();
    #pragma unroll
    for (int k = 0; k < 16; ++k){
      float4 a4 = *(const float4*)&As[k][tm*4];
      float bv[NW];
      #pragma unroll
      for (int j = 0; j < NW; j += 4){
        float4 b4 = *(const float4*)&Bs[k][tn*NW + j];
        bv[j] = b4.x; bv[j+1] = b4.y; bv[j+2] = b4.z; bv[j+3] = b4.w;
      }
      #pragma unroll
      for (int j = 0; j < NW; ++j){
        acc[0][j] += a4.x*bv[j];
        acc[1][j] += a4.y*bv[j];
        acc[2][j] += a4.z*bv[j];
        acc[3][j] += a4.w*bv[j];
      }
    }
    __syncthreads();
  }
  #pragma unroll
  for (int i = 0; i < 4; ++i){
    long roff = (long)(m0 + tm*4 + i)*ldc + n0 + tn*NW;
    #pragma unroll
    for (int j = 0; j < NW; ++j) storeC(Cp + roff + j, acc[i][j]);
  }
}

// ---------------------------------------------------------------------------
// RoPE on q_big (bf16, in place).  Layout [b,s][h*1536+q]; pairs (q, q+768).
__global__ __launch_bounds__(256) void rope_q_kernel(
    __hip_bfloat16* __restrict__ qb,
    const float* __restrict__ sq, const float* __restrict__ cq)
{
  int idx = blockIdx.x*256 + threadIdx.x;   // < 2*1024*16*768
  int row = idx / 768;
  int q = idx - row*768;
  int s = (row >> 4) & 1023;                // row = (b*1024+s)*16 + h
  long base = (long)row*1536;
  float xl = __bfloat162float(qb[base+q]);
  float xh = __bfloat162float(qb[base+q+768]);
  int tb = s*1536 + q;
  float yl = xl*cq[tb]     - xh*sq[tb];
  float yh = xh*cq[tb+768] + xl*sq[tb+768];
  qb[base+q]     = __float2bfloat16(yl);
  qb[base+q+768] = __float2bfloat16(yh);
}

// RoPE on kv_c -> kv_r (fp32).  [b,l,512]; pairs (d, d+256).
__global__ __launch_bounds__(256) void rope_k_kernel(
    const float* __restrict__ kc,
    const float* __restrict__ sk, const float* __restrict__ ck,
    float* __restrict__ kvr)
{
  int idx = blockIdx.x*256 + threadIdx.x;   // < 2*1024*256
  int row = idx >> 8;
  int d = idx & 255;
  int l = row & 1023;
  long base = (long)row*512;
  float xl = kc[base+d], xh = kc[base+d+256];
  int tb = l*512 + d;
  kvr[base+d]     = xl*ck[tb]     - xh*sk[tb];
  kvr[base+d+256] = xh*ck[tb+256] + xl*sk[tb+256];
}

// ---------------------------------------------------------------------------
// Flash attention v2 with absorbed V' (= kv_r @ w_kc_kv^T, [B,H,L,128] fp32).
// Per WG: (b, h, 64 q-rows).  Writes ctx_lat[b,s][h*128+k] directly (fp32).
// Thread map: si = t>>3 (rows si, si+32), dg = t&7 (d cols j4*32+dg*4).
// Score cols per thread: l in {dg, dg+8, dg+16, dg+24} -> K-row reads hit
// banks 4*dg apart (row stride 68 words) = conflict-free.
__global__ __launch_bounds__(256) void flash_attn2(
    const float* __restrict__ qr, const float* __restrict__ kr,
    const float* __restrict__ vp, float* __restrict__ ctx_lat)
{
  const int b = blockIdx.z, h = blockIdx.y, s0 = blockIdx.x*64;
  const int t = threadIdx.x;
  __shared__ float Qs[64][68];
  __shared__ float Ks[32][68];
  __shared__ float Vs[32][132];
  __shared__ float Ss[64][37];
  __shared__ float mi[64], li[64], alp[64];

  const float* qbase = qr + (((long)(b*16+h))*1024 + s0)*64;
  const float* kbase = kr + ((long)(b*16+h))*65536;
  const float* vbase = vp + (((long)(b*16+h))*1024)*128;

  #pragma unroll
  for (int e = 0; e < 4; ++e){
    int f = t + e*256;
    int row = f >> 4, col = (f & 15)*4;
    *(float4*)&Qs[row][col] = *(const float4*)(qbase + (long)row*64 + col);
  }
  if (t < 64){ mi[t] = -3e38f; li[t] = 0.f; }

  const int si = t >> 3, dg = t & 7;
  float acc0[16], acc1[16];
  #pragma unroll
  for (int j = 0; j < 16; ++j){ acc0[j] = 0.f; acc1[j] = 0.f; }

  for (int l0 = 0; l0 < 1024; l0 += 32){
    #pragma unroll
    for (int e = 0; e < 2; ++e){
      int f = t + e*256;
      int row = f >> 4, col = (f & 15)*4;
      *(float4*)&Ks[row][col] = *(const float4*)(kbase + (long)(l0+row)*64 + col);
    }
    #pragma unroll
    for (int e = 0; e < 4; ++e){
      int f = t + e*256;
      int row = f >> 5, col = (f & 31)*4;
      *(float4*)&Vs[row][col] = *(const float4*)(vbase + (long)(l0+row)*128 + col);
    }
    __syncthreads();
    // scores: rows {si, si+32} x cols {dg, dg+8, dg+16, dg+24}
    {
      float s00=0.f,s01=0.f,s02=0.f,s03=0.f;
      float s10=0.f,s11=0.f,s12=0.f,s13=0.f;
      #pragma unroll
      for (int r4 = 0; r4 < 16; ++r4){
        float4 qa = *(const float4*)&Qs[si][r4*4];
        float4 qb = *(const float4*)&Qs[si+32][r4*4];
        float4 k0 = *(const float4*)&Ks[dg   ][r4*4];
        float4 k1 = *(const float4*)&Ks[dg+ 8][r4*4];
        float4 k2 = *(const float4*)&Ks[dg+16][r4*4];
        float4 k3 = *(const float4*)&Ks[dg+24][r4*4];
        s00 += qa.x*k0.x+qa.y*k0.y+qa.z*k0.z+qa.w*k0.w;
        s01 += qa.x*k1.x+qa.y*k1.y+qa.z*k1.z+qa.w*k1.w;
        s02 += qa.x*k2.x+qa.y*k2.y+qa.z*k2.z+qa.w*k2.w;
        s03 += qa.x*k3.x+qa.y*k3.y+qa.z*k3.z+qa.w*k3.w;
        s10 += qb.x*k0.x+qb.y*k0.y+qb.z*k0.z+qb.w*k0.w;
        s11 += qb.x*k1.x+qb.y*k1.y+qb.z*k1.z+qb.w*k1.w;
        s12 += qb.x*k2.x+qb.y*k2.y+qb.z*k2.z+qb.w*k2.w;
        s13 += qb.x*k3.x+qb.y*k3.y+qb.z*k3.z+qb.w*k3.w;
      }
      Ss[si][dg]    = s00; Ss[si][dg+8]    = s01;
      Ss[si][dg+16] = s02; Ss[si][dg+24]   = s03;
      Ss[si+32][dg]    = s10; Ss[si+32][dg+8]  = s11;
      Ss[si+32][dg+16] = s12; Ss[si+32][dg+24] = s13;
    }
    __syncthreads();
    if (t < 64){
      float mold = mi[t], mx = mold;
      #pragma unroll 8
      for (int l = 0; l < 32; ++l) mx = fmaxf(mx, Ss[t][l]);
      float a = __expf(mold - mx);
      float sum = 0.f;
      #pragma unroll 8
      for (int l = 0; l < 32; ++l){
        float p = __expf(Ss[t][l] - mx);
        Ss[t][l] = p; sum += p;
      }
      li[t] = li[t]*a + sum; mi[t] = mx; alp[t] = a;
    }
    __syncthreads();
    {
      float a0 = alp[si], a1 = alp[si+32];
      #pragma unroll
      for (int j = 0; j < 16; ++j){ acc0[j] *= a0; acc1[j] *= a1; }
    }
    #pragma unroll 4
    for (int l = 0; l < 32; ++l){
      float p0 = Ss[si][l], p1 = Ss[si+32][l];
      #pragma unroll
      for (int j4 = 0; j4 < 4; ++j4){
        float4 v = *(const float4*)&Vs[l][j4*32 + dg*4];
        acc0[j4*4+0] += p0*v.x; acc0[j4*4+1] += p0*v.y;
        acc0[j4*4+2] += p0*v.z; acc0[j4*4+3] += p0*v.w;
        acc1[j4*4+0] += p1*v.x; acc1[j4*4+1] += p1*v.y;
        acc1[j4*4+2] += p1*v.z; acc1[j4*4+3] += p1*v.w;
      }
    }
    __syncthreads();
  }
  float inv0 = 1.f/li[si], inv1 = 1.f/li[si+32];
  float* c0 = ctx_lat + ((long)(b*1024 + s0 + si))*2048 + h*128;
  float* c1 = ctx_lat + ((long)(b*1024 + s0 + si + 32))*2048 + h*128;
  #pragma unroll
  for (int j4 = 0; j4 < 4; ++j4){
    float4 o0 = make_float4(acc0[j4*4+0]*inv0, acc0[j4*4+1]*inv0,
                            acc0[j4*4+2]*inv0, acc0[j4*4+3]*inv0);
    float4 o1 = make_float4(acc1[j4*4+0]*inv1, acc1[j4*4+1]*inv1,
                            acc1[j4*4+2]*inv1, acc1[j4*4+3]*inv1);
    *(float4*)(c0 + j4*32 + dg*4) = o0;
    *(float4*)(c1 + j4*32 + dg*4) = o1;
  }
}

// ---------------------------------------------------------------------------
extern "C" void kernel_launch(void* const* d_in, const int* in_sizes, int n_in,
                              void* d_out, int out_size, void* d_ws, size_t ws_size,
                              hipStream_t stream)
{
  const float* hidden_q = (const float*)d_in[0];   // [2,1024,2048]
  const float* kv_c     = (const float*)d_in[1];   // [2,1024,512]
  const float* Wq       = (const float*)d_in[2];   // [2048,2048]
  const float* w_kc_q   = (const float*)d_in[3];   // [16,128,1536]
  const float* w_kc_kv  = (const float*)d_in[4];   // [16,128,512]
  const float* W_qr     = (const float*)d_in[5];   // [16,1536,64]
  const float* W_kr     = (const float*)d_in[6];   // [16,512,64]
  const float* Wo       = (const float*)d_in[7];   // [2048,2048]
  float* out = (float*)d_out;

  char* wsb = (char*)d_ws;
  size_t off = 0;
  auto take = [&](size_t bytes)->void*{
    void* p = wsb + off; off += (bytes + 255) & ~(size_t)255; return p;
  };
  float* q_r   = (float*)take(2097152ull*4);   // [B,H,S,64]
  float* k_r   = (float*)take(2097152ull*4);   // [B,H,L,64]
  float* kv_r  = (float*)take(1048576ull*4);   // [B,L,512]
  float* sink  = (float*)take(524288ull*4);
  float* cosk  = (float*)take(524288ull*4);
  float* sinq  = (float*)take(1572864ull*4);
  float* cosq  = (float*)take(1572864ull*4);
  float* q_hk  = (float*)take(4194304ull*4);   // [B*S, H*128]
  char*  bigr  = (char*)take(100663296ull);    // q_big bf16 region (aliased later)
  __hip_bfloat16* q_big = (__hip_bfloat16*)bigr;           // [B,S][H*1536]
  float* ctx_lat = (float*)(bigr + 33554432);              // [B*S, H*128] fp32 (16.8MB)
  float* vprime  = (float*)(bigr + 58720256);              // [B,H,L,128] fp32 (16.8MB)

  // 1) tables
  build_tables<<<4096, 256, 0, stream>>>(sinq, cosq, sink, cosk);

  // 2) q_hk = hidden_q @ Wq^T   (M=2048,N=2048,K=2048)
  gemm64<float,float,true,128><<<dim3(32,16,1),256,0,stream>>>(
      hidden_q, Wq, q_hk, 2048, 2048,2048,2048, 1, 0,0, 0,0, 0,0);

  // 3) q_big[b,s][h*1536+q] = q_hk @ w_kc_q[h]  (per (b,h): M=1024,N=1536,K=128)
  gemm64<float,__hip_bfloat16,false,128><<<dim3(16,12,32),256,0,stream>>>(
      q_hk, w_kc_q, q_big, 128, 2048,1536,24576, 16,
      2097152,128, 0,196608, 25165824,1536);

  // 4) RoPE q_big in place
  rope_q_kernel<<<98304, 256, 0, stream>>>(q_big, sinq, cosq);

  // 5) q_r[b,h,s,r] = q_big @ W_qr[h]  (per (b,h): M=1024,N=64,K=1536)
  gemm64<__hip_bfloat16,float,false,64><<<dim3(16,1,32),256,0,stream>>>(
      q_big, W_qr, q_r, 1536, 24576,64,64, 16,
      25165824,1536, 0,98304, 1048576,65536);

  // 6) kv_r = RoPE(kv_c)
  rope_k_kernel<<<2048, 256, 0, stream>>>(kv_c, sink, cosk, kv_r);

  // 7) k_r[b,h,l,r] = kv_r[b] @ W_kr[h]  (per (b,h): M=1024,N=64,K=512)
  gemm64<float,float,false,64><<<dim3(16,1,32),256,0,stream>>>(
      kv_r, W_kr, k_r, 512, 512,64,64, 16,
      524288,0, 0,32768, 1048576,65536);

  // 7b) V'[b,h,l,k] = kv_r[b] @ w_kc_kv[h]^T  (per (b,h): M=1024,N=128,K=512)
  //     (absorbs the post-attention decompression into V)
  gemm64<float,float,true,128><<<dim3(16,1,32),256,0,stream>>>(
      kv_r, w_kc_kv, vprime, 512, 512,512,128, 16,
      524288,0, 0,65536, 2097152,131072);

  // 8) flash attention over V' -> ctx_lat[b,s][h*128+k] (fp32), step 9 absorbed
  flash_attn2<<<dim3(16,16,2),256,0,stream>>>(q_r, k_r, vprime, ctx_lat);

  // 10) out = ctx_lat @ Wo^T  (M=2048,N=2048,K=2048)
  gemm64<float,float,true,128><<<dim3(32,16,1),256,0,stream>>>(
      ctx_lat, Wo, out, 2048, 2048,2048,2048, 1, 0,0, 0,0, 0,0);
}

// Round 3
// 745.202 us; speedup vs baseline: 2.7861x; 1.7343x over previous
//
#include <hip/hip_runtime.h>
#include <hip/hip_bf16.h>

// B=2, S=1024, L=1024, DIM_Q=2048, H=16, K=128, D_C=512, D_CQ=1536, R=64

typedef unsigned short ushort_t;
typedef __attribute__((ext_vector_type(8))) short short8;
typedef __attribute__((ext_vector_type(4))) float f32x4;

__device__ __forceinline__ float4 load4(const float* p){ return *(const float4*)p; }
__device__ __forceinline__ unsigned short f2bs(float v){
  __hip_bfloat16 b = __float2bfloat16(v);
  return *reinterpret_cast<unsigned short*>(&b);
}
__device__ __forceinline__ void storeC(float* p, float v){ *p = v; }
__device__ __forceinline__ void storeC(unsigned short* p, float v){ *p = f2bs(v); }

// async global->LDS, 16B per lane.  LDS dest = wave-uniform base + lane*16.
__device__ __forceinline__ void gl_lds16(const void* g, void* l){
  __builtin_amdgcn_global_load_lds(
      (const __attribute__((address_space(1))) unsigned int*)g,
      (__attribute__((address_space(3))) unsigned int*)l, 16, 0, 0);
}

// ---------------------------------------------------------------------------
__global__ __launch_bounds__(256) void build_tables(
    float* __restrict__ sinq, float* __restrict__ cosq,
    float* __restrict__ sink, float* __restrict__ cosk)
{
  int idx = blockIdx.x*256 + threadIdx.x;
  if (idx < 1024*768){
    int s = idx / 768, j = idx % 768;
    float f = (float)s * powf(10000.f, (-2.f*j)/1536.f);
    float sv = sinf(f), cv = cosf(f);
    int base = s*1536 + 2*j;
    sinq[base] = sv; sinq[base+1] = sv;
    cosq[base] = cv; cosq[base+1] = cv;
  } else {
    int k = idx - 1024*768;
    int l = k / 256, j = k % 256;
    float f = (float)l * powf(10000.f, (-2.f*j)/512.f);
    float sv = sinf(f), cv = cosf(f);
    int base = l*512 + 2*j;
    sink[base] = sv; sink[base+1] = sv;
    cosk[base] = cv; cosk[base+1] = cv;
  }
}

// ---------------------------------------------------------------------------
// fp32 -> bf16 straight convert (n4 = n/4 groups)
__global__ __launch_bounds__(256) void cvt_bf16(
    const float* __restrict__ in, unsigned short* __restrict__ out, int n4)
{
  int i = blockIdx.x*256 + threadIdx.x;
  if (i < n4){
    float4 v = *(const float4*)(in + (long)i*4);
    ushort4 u; u.x=f2bs(v.x); u.y=f2bs(v.y); u.z=f2bs(v.z); u.w=f2bs(v.w);
    *(ushort4*)(out + (long)i*4) = u;
  }
}

// fp32 [R,Cn] -> bf16 [Cn,R] per head (32x32 LDS tiles)
__global__ __launch_bounds__(256) void transpose_cvt(
    const float* __restrict__ in, unsigned short* __restrict__ out,
    int R, int Cn, long sIn, long sOut)
{
  __shared__ float tile[32][33];
  const float* ip = in + (long)blockIdx.z*sIn;
  unsigned short* op = out + (long)blockIdx.z*sOut;
  int c0 = blockIdx.x*32, r0 = blockIdx.y*32;
  int tr = threadIdx.x>>5, tc = threadIdx.x&31;
  #pragma unroll
  for (int i=0;i<4;i++)
    tile[tr+i*8][tc] = ip[(long)(r0+tr+i*8)*Cn + c0+tc];
  __syncthreads();
  #pragma unroll
  for (int i=0;i<4;i++)
    op[(long)(c0+tr+i*8)*R + r0+tc] = f2bs(tile[tc][tr+i*8]);
}

// ---------------------------------------------------------------------------
// bf16 MFMA GEMM (NT): C[m,n] = sum_k A[m,k]*B[n,k], A/B bf16, C float or bf16.
// Tile BM x BN x 32; 256 threads = 4 waves; wave grid (BM/WM)x(BN/WN); per wave
// (WM/16)x(WN/16) frags of mfma_f32_16x16x32_bf16.
// LDS layout [kq][row][8] so global_load_lds staging is lane-contiguous and
// frag ds_read_b128 is only 2-way bank-aliased (free).
template<int BM,int BN,int WM,int WN,typename TC>
__global__ __launch_bounds__(256) void gemm_mfma(
    const unsigned short* __restrict__ A, const unsigned short* __restrict__ B,
    TC* __restrict__ C,
    int Kd, int lda, int ldb, int ldc, int Hb,
    long sAb, long sAh, long sBb, long sBh, long sCb, long sCh)
{
  constexpr int MF = WM/16, NF = WN/16;
  constexpr int WGM = BM/WM;
  constexpr int AOPS = (4*BM)/256;
  constexpr int BOPS = (4*BN)/256;

  const int z = blockIdx.z, bb = z/Hb, hh = z - bb*Hb;
  const unsigned short* Ap = A + bb*sAb + hh*sAh;
  const unsigned short* Bp = B + bb*sBb + hh*sBh;
  TC* Cp = C + bb*sCb + hh*sCh;
  const int m0 = blockIdx.x*BM, n0 = blockIdx.y*BN;
  const int t = threadIdx.x, w = t>>6, l = t&63;
  const int wm0 = (w % WGM)*WM, wn0 = (w / WGM)*WN;
  const int lq = l>>4, lm = l&15;

  __shared__ __align__(16) unsigned short As[4*BM*8];
  __shared__ __align__(16) unsigned short Bs[4*BN*8];

  f32x4 acc[MF][NF];
  #pragma unroll
  for (int mf=0; mf<MF; ++mf)
    #pragma unroll
    for (int nf=0; nf<NF; ++nf)
      acc[mf][nf] = f32x4{0.f,0.f,0.f,0.f};

  for (int k0 = 0; k0 < Kd; k0 += 32){
    #pragma unroll
    for (int o = 0; o < AOPS; ++o){
      int g = o*256 + t;
      int row = g & (BM-1), kq = g / BM;
      gl_lds16(Ap + (long)(m0+row)*lda + k0 + kq*8, &As[(o*256 + w*64)*8]);
    }
    #pragma unroll
    for (int o = 0; o < BOPS; ++o){
      int g = o*256 + t;
      int row = g & (BN-1), kq = g / BN;
      gl_lds16(Bp + (long)(n0+row)*ldb + k0 + kq*8, &Bs[(o*256 + w*64)*8]);
    }
    __syncthreads();
    short8 af[MF], bfr[NF];
    #pragma unroll
    for (int mf=0; mf<MF; ++mf)
      af[mf] = *(const short8*)&As[(lq*BM + wm0 + mf*16 + lm)*8];
    #pragma unroll
    for (int nf=0; nf<NF; ++nf)
      bfr[nf] = *(const short8*)&Bs[(lq*BN + wn0 + nf*16 + lm)*8];
    #pragma unroll
    for (int mf=0; mf<MF; ++mf)
      #pragma unroll
      for (int nf=0; nf<NF; ++nf)
        acc[mf][nf] = __builtin_amdgcn_mfma_f32_16x16x32_bf16(
            af[mf], bfr[nf], acc[mf][nf], 0, 0, 0);
    __syncthreads();
  }

  #pragma unroll
  for (int mf=0; mf<MF; ++mf){
    #pragma unroll
    for (int nf=0; nf<NF; ++nf){
      int row = m0 + wm0 + mf*16 + lq*4;
      int col = n0 + wn0 + nf*16 + lm;
      #pragma unroll
      for (int r=0; r<4; ++r)
        storeC(&Cp[(long)(row+r)*ldc + col], acc[mf][nf][r]);
    }
  }
}

// ---------------------------------------------------------------------------
// fp32 NN GEMM (kept only for k_r, step 7)
template<int BN>
__global__ __launch_bounds__(256) void gemm64f(
    const float* __restrict__ A, const float* __restrict__ B, float* __restrict__ C,
    int Kd, int lda, int ldb, int ldc, int Hb,
    long sAb, long sAh, long sBb, long sBh, long sCb, long sCh)
{
  constexpr int NW = BN/16;
  const int z = blockIdx.z;
  const int bb = z / Hb, hh = z % Hb;
  const float* Ap = A + (long)bb*sAb + (long)hh*sAh;
  const float* Bp = B + (long)bb*sBb + (long)hh*sBh;
  float* Cp = C + (long)bb*sCb + (long)hh*sCh;
  const int m0 = blockIdx.x*64, n0 = blockIdx.y*BN;

  __shared__ float Asd[16][68];
  __shared__ float Bsd[16][BN+4];

  const int t = threadIdx.x;
  const int tm = t >> 4, tn = t & 15;
  float acc[4][NW];
  #pragma unroll
  for (int i = 0; i < 4; ++i)
    #pragma unroll
    for (int j = 0; j < NW; ++j) acc[i][j] = 0.f;

  const int am = t >> 2, ak = (t & 3)*4;

  for (int k0 = 0; k0 < Kd; k0 += 16){
    {
      float4 av = load4(Ap + (long)(m0+am)*lda + k0 + ak);
      Asd[ak+0][am] = av.x; Asd[ak+1][am] = av.y;
      Asd[ak+2][am] = av.z; Asd[ak+3][am] = av.w;
    }
    {
      constexpr int NQ = BN/4;
      int kk = t / NQ, nq = (t % NQ)*4;
      float4 bv = load4(Bp + (long)(k0+kk)*ldb + n0 + nq);
      *(float4*)&Bsd[kk][nq] = bv;
      if (BN == 64){
        int kk2 = kk + 16*256/(BN*4);
        (void)kk2;
      }
      // BN=64: 256 threads cover 16x64 exactly in one pass
    }
    __syncthreads();
    #pragma unroll
    for (int k = 0; k < 16; ++k){
      float4 a4 = *(const float4*)&Asd[k][tm*4];
      float bv[NW];
      #pragma unroll
      for (int j = 0; j < NW; j += 4){
        float4 b4 = *(const float4*)&Bsd[k][tn*NW + j];
        bv[j] = b4.x; bv[j+1] = b4.y; bv[j+2] = b4.z; bv[j+3] = b4.w;
      }
      #pragma unroll
      for (int j = 0; j < NW; ++j){
        acc[0][j] += a4.x*bv[j];
        acc[1][j] += a4.y*bv[j];
        acc[2][j] += a4.z*bv[j];
        acc[3][j] += a4.w*bv[j];
      }
    }
    __syncthreads();
  }
  #pragma unroll
  for (int i = 0; i < 4; ++i){
    long roff = (long)(m0 + tm*4 + i)*ldc + n0 + tn*NW;
    #pragma unroll
    for (int j = 0; j < NW; ++j) storeC(Cp + roff + j, acc[i][j]);
  }
}

// ---------------------------------------------------------------------------
// RoPE on q_big (bf16, in place).  Layout [b,s][h*1536+q]; pairs (q, q+768).
__global__ __launch_bounds__(256) void rope_q_kernel(
    unsigned short* __restrict__ qb,
    const float* __restrict__ sq, const float* __restrict__ cq)
{
  int idx = blockIdx.x*256 + threadIdx.x;   // < 2*1024*16*768
  int row = idx / 768;
  int q = idx - row*768;
  int s = (row >> 4) & 1023;
  long base = (long)row*1536;
  float xl = __uint_as_float((unsigned)qb[base+q] << 16);
  float xh = __uint_as_float((unsigned)qb[base+q+768] << 16);
  int tb = s*1536 + q;
  float yl = xl*cq[tb]     - xh*sq[tb];
  float yh = xh*cq[tb+768] + xl*sq[tb+768];
  qb[base+q]     = f2bs(yl);
  qb[base+q+768] = f2bs(yh);
}

// RoPE on kv_c -> kv_r fp32 + bf16.  [b,l,512]; pairs (d, d+256).
__global__ __launch_bounds__(256) void rope_k_kernel(
    const float* __restrict__ kc,
    const float* __restrict__ sk, const float* __restrict__ ck,
    float* __restrict__ kvr, unsigned short* __restrict__ kvrb)
{
  int idx = blockIdx.x*256 + threadIdx.x;   // < 2*1024*256
  int row = idx >> 8;
  int d = idx & 255;
  int l = row & 1023;
  long base = (long)row*512;
  float xl = kc[base+d], xh = kc[base+d+256];
  int tb = l*512 + d;
  float y0 = xl*ck[tb]     - xh*sk[tb];
  float y1 = xh*ck[tb+256] + xl*sk[tb+256];
  kvr[base+d]      = y0;
  kvr[base+d+256]  = y1;
  kvrb[base+d]     = f2bs(y0);
  kvrb[base+d+256] = f2bs(y1);
}

// ---------------------------------------------------------------------------
// Flash attention with absorbed V' ([B,H,L,128] fp32) -> ctx_lat bf16.
__global__ __launch_bounds__(256) void flash_attn2(
    const float* __restrict__ qr, const float* __restrict__ kr,
    const float* __restrict__ vp, unsigned short* __restrict__ ctx_lat)
{
  const int b = blockIdx.z, h = blockIdx.y, s0 = blockIdx.x*64;
  const int t = threadIdx.x;
  __shared__ float Qs[64][68];
  __shared__ float Ks[32][68];
  __shared__ float Vs[32][132];
  __shared__ float Ss[64][37];
  __shared__ float mi[64], li[64], alp[64];

  const float* qbase = qr + (((long)(b*16+h))*1024 + s0)*64;
  const float* kbase = kr + ((long)(b*16+h))*65536;
  const float* vbase = vp + (((long)(b*16+h))*1024)*128;

  #pragma unroll
  for (int e = 0; e < 4; ++e){
    int f = t + e*256;
    int row = f >> 4, col = (f & 15)*4;
    *(float4*)&Qs[row][col] = *(const float4*)(qbase + (long)row*64 + col);
  }
  if (t < 64){ mi[t] = -3e38f; li[t] = 0.f; }

  const int si = t >> 3, dg = t & 7;
  float acc0[16], acc1[16];
  #pragma unroll
  for (int j = 0; j < 16; ++j){ acc0[j] = 0.f; acc1[j] = 0.f; }

  for (int l0 = 0; l0 < 1024; l0 += 32){
    #pragma unroll
    for (int e = 0; e < 2; ++e){
      int f = t + e*256;
      int row = f >> 4, col = (f & 15)*4;
      *(float4*)&Ks[row][col] = *(const float4*)(kbase + (long)(l0+row)*64 + col);
    }
    #pragma unroll
    for (int e = 0; e < 4; ++e){
      int f = t + e*256;
      int row = f >> 5, col = (f & 31)*4;
      *(float4*)&Vs[row][col] = *(const float4*)(vbase + (long)(l0+row)*128 + col);
    }
    __syncthreads();
    {
      float s00=0.f,s01=0.f,s02=0.f,s03=0.f;
      float s10=0.f,s11=0.f,s12=0.f,s13=0.f;
      #pragma unroll
      for (int r4 = 0; r4 < 16; ++r4){
        float4 qa = *(const float4*)&Qs[si][r4*4];
        float4 qb = *(const float4*)&Qs[si+32][r4*4];
        float4 k0 = *(const float4*)&Ks[dg   ][r4*4];
        float4 k1 = *(const float4*)&Ks[dg+ 8][r4*4];
        float4 k2 = *(const float4*)&Ks[dg+16][r4*4];
        float4 k3 = *(const float4*)&Ks[dg+24][r4*4];
        s00 += qa.x*k0.x+qa.y*k0.y+qa.z*k0.z+qa.w*k0.w;
        s01 += qa.x*k1.x+qa.y*k1.y+qa.z*k1.z+qa.w*k1.w;
        s02 += qa.x*k2.x+qa.y*k2.y+qa.z*k2.z+qa.w*k2.w;
        s03 += qa.x*k3.x+qa.y*k3.y+qa.z*k3.z+qa.w*k3.w;
        s10 += qb.x*k0.x+qb.y*k0.y+qb.z*k0.z+qb.w*k0.w;
        s11 += qb.x*k1.x+qb.y*k1.y+qb.z*k1.z+qb.w*k1.w;
        s12 += qb.x*k2.x+qb.y*k2.y+qb.z*k2.z+qb.w*k2.w;
        s13 += qb.x*k3.x+qb.y*k3.y+qb.z*k3.z+qb.w*k3.w;
      }
      Ss[si][dg]    = s00; Ss[si][dg+8]    = s01;
      Ss[si][dg+16] = s02; Ss[si][dg+24]   = s03;
      Ss[si+32][dg]    = s10; Ss[si+32][dg+8]  = s11;
      Ss[si+32][dg+16] = s12; Ss[si+32][dg+24] = s13;
    }
    __syncthreads();
    if (t < 64){
      float mold = mi[t], mx = mold;
      #pragma unroll 8
      for (int l = 0; l < 32; ++l) mx = fmaxf(mx, Ss[t][l]);
      float a = __expf(mold - mx);
      float sum = 0.f;
      #pragma unroll 8
      for (int l = 0; l < 32; ++l){
        float p = __expf(Ss[t][l] - mx);
        Ss[t][l] = p; sum += p;
      }
      li[t] = li[t]*a + sum; mi[t] = mx; alp[t] = a;
    }
    __syncthreads();
    {
      float a0 = alp[si], a1 = alp[si+32];
      #pragma unroll
      for (int j = 0; j < 16; ++j){ acc0[j] *= a0; acc1[j] *= a1; }
    }
    #pragma unroll 4
    for (int l = 0; l < 32; ++l){
      float p0 = Ss[si][l], p1 = Ss[si+32][l];
      #pragma unroll
      for (int j4 = 0; j4 < 4; ++j4){
        float4 v = *(const float4*)&Vs[l][j4*32 + dg*4];
        acc0[j4*4+0] += p0*v.x; acc0[j4*4+1] += p0*v.y;
        acc0[j4*4+2] += p0*v.z; acc0[j4*4+3] += p0*v.w;
        acc1[j4*4+0] += p1*v.x; acc1[j4*4+1] += p1*v.y;
        acc1[j4*4+2] += p1*v.z; acc1[j4*4+3] += p1*v.w;
      }
    }
    __syncthreads();
  }
  float inv0 = 1.f/li[si], inv1 = 1.f/li[si+32];
  unsigned short* c0 = ctx_lat + ((long)(b*1024 + s0 + si))*2048 + h*128;
  unsigned short* c1 = ctx_lat + ((long)(b*1024 + s0 + si + 32))*2048 + h*128;
  #pragma unroll
  for (int j4 = 0; j4 < 4; ++j4){
    ushort4 o0, o1;
    o0.x = f2bs(acc0[j4*4+0]*inv0); o0.y = f2bs(acc0[j4*4+1]*inv0);
    o0.z = f2bs(acc0[j4*4+2]*inv0); o0.w = f2bs(acc0[j4*4+3]*inv0);
    o1.x = f2bs(acc1[j4*4+0]*inv1); o1.y = f2bs(acc1[j4*4+1]*inv1);
    o1.z = f2bs(acc1[j4*4+2]*inv1); o1.w = f2bs(acc1[j4*4+3]*inv1);
    *(ushort4*)(c0 + j4*32 + dg*4) = o0;
    *(ushort4*)(c1 + j4*32 + dg*4) = o1;
  }
}

// ---------------------------------------------------------------------------
extern "C" void kernel_launch(void* const* d_in, const int* in_sizes, int n_in,
                              void* d_out, int out_size, void* d_ws, size_t ws_size,
                              hipStream_t stream)
{
  const float* hidden_q = (const float*)d_in[0];   // [2,1024,2048]
  const float* kv_c     = (const float*)d_in[1];   // [2,1024,512]
  const float* Wq       = (const float*)d_in[2];   // [2048,2048]
  const float* w_kc_q   = (const float*)d_in[3];   // [16,128,1536]
  const float* w_kc_kv  = (const float*)d_in[4];   // [16,128,512]
  const float* W_qr     = (const float*)d_in[5];   // [16,1536,64]
  const float* W_kr     = (const float*)d_in[6];   // [16,512,64]
  const float* Wo       = (const float*)d_in[7];   // [2048,2048]
  float* out = (float*)d_out;

  char* wsb = (char*)d_ws;
  size_t off = 0;
  auto take = [&](size_t bytes)->void*{
    void* p = wsb + off; off += (bytes + 255) & ~(size_t)255; return p;
  };
  float* q_r    = (float*)take(8388608);            // [B,H,S,64] fp32
  float* k_r    = (float*)take(8388608);            // [B,H,L,64] fp32
  float* kv_r   = (float*)take(4194304);            // [B,L,512] fp32
  unsigned short* kv_rb = (unsigned short*)take(2097152);   // bf16 copy
  float* sink   = (float*)take(2097152);
  float* cosk   = (float*)take(2097152);
  float* sinq   = (float*)take(6291456);
  float* cosq   = (float*)take(6291456);
  unsigned short* q_hk    = (unsigned short*)take(8388608); // [B*S,2048] bf16
  unsigned short* hiddenb = (unsigned short*)take(8388608); // bf16 hidden_q
  unsigned short* Wqb     = (unsigned short*)take(8388608); // bf16 Wq
  unsigned short* wkcqT   = (unsigned short*)take(6291456); // [16][1536][128] bf16
  unsigned short* WqrT    = (unsigned short*)take(3145728); // [16][64][1536] bf16
  unsigned short* wkckvb  = (unsigned short*)take(2097152); // [16][128][512] bf16
  char* bigr = (char*)take(100663296);
  unsigned short* q_big   = (unsigned short*)bigr;          // [B*S][24576] bf16
  unsigned short* Wob     = (unsigned short*)bigr;          // bf16 Wo (after q_big dead)
  unsigned short* ctx_lat = (unsigned short*)(bigr + 8388608);  // [B*S][2048] bf16
  float* vprime = (float*)(bigr + 16777216);                // [B,H,L,128] fp32

  // tables + input converts
  build_tables<<<4096, 256, 0, stream>>>(sinq, cosq, sink, cosk);
  cvt_bf16<<<4096, 256, 0, stream>>>(hidden_q, hiddenb, 1048576);
  cvt_bf16<<<4096, 256, 0, stream>>>(Wq, Wqb, 1048576);
  cvt_bf16<<<1024, 256, 0, stream>>>(w_kc_kv, wkckvb, 262144);
  transpose_cvt<<<dim3(48,4,16), 256, 0, stream>>>(w_kc_q, wkcqT, 128, 1536, 196608, 196608);
  transpose_cvt<<<dim3(2,48,16), 256, 0, stream>>>(W_qr, WqrT, 1536, 64, 98304, 98304);

  // 2) q_hk = hidden @ Wq^T   (2048x2048x2048) -> bf16
  gemm_mfma<128,128,64,64,unsigned short><<<dim3(16,16,1),256,0,stream>>>(
      hiddenb, Wqb, q_hk, 2048, 2048,2048,2048, 1, 0,0, 0,0, 0,0);

  // 3) q_big = q_hk @ w_kc_q_T  (per (b,h): 1024x1536x128) -> bf16
  gemm_mfma<128,128,64,64,unsigned short><<<dim3(8,12,32),256,0,stream>>>(
      q_hk, wkcqT, q_big, 128, 2048,128,24576, 16,
      2097152,128, 0,196608, 25165824,1536);

  // 4) RoPE q_big in place
  rope_q_kernel<<<98304, 256, 0, stream>>>(q_big, sinq, cosq);

  // 5) q_r = q_big @ W_qr_T  (per (b,h): 1024x64x1536) -> fp32
  gemm_mfma<128,64,32,64,float><<<dim3(8,1,32),256,0,stream>>>(
      q_big, WqrT, q_r, 1536, 24576,1536,64, 16,
      25165824,1536, 0,98304, 1048576,65536);

  // Wo convert (aliases dead q_big region — must come after step 5)
  cvt_bf16<<<4096, 256, 0, stream>>>(Wo, Wob, 1048576);

  // 6) kv_r = RoPE(kv_c)  (fp32 + bf16)
  rope_k_kernel<<<2048, 256, 0, stream>>>(kv_c, sink, cosk, kv_r, kv_rb);

  // 7) k_r = kv_r @ W_kr  (fp32, per (b,h): 1024x64x512) — keep fp32 for score precision
  gemm64f<64><<<dim3(16,1,32),256,0,stream>>>(
      kv_r, W_kr, k_r, 512, 512,64,64, 16,
      524288,0, 0,32768, 1048576,65536);

  // 7b) V' = kv_r @ w_kc_kv^T  (per (b,h): 1024x128x512) -> fp32
  gemm_mfma<128,128,64,64,float><<<dim3(8,1,32),256,0,stream>>>(
      kv_rb, wkckvb, vprime, 512, 512,512,128, 16,
      524288,0, 0,65536, 2097152,131072);

  // 8) flash attention -> ctx_lat bf16
  flash_attn2<<<dim3(16,16,2),256,0,stream>>>(q_r, k_r, vprime, ctx_lat);

  // 10) out = ctx_lat @ Wo^T  (2048x2048x2048) -> fp32
  gemm_mfma<128,128,64,64,float><<<dim3(16,16,1),256,0,stream>>>(
      ctx_lat, Wob, out, 2048, 2048,2048,2048, 1, 0,0, 0,0, 0,0);
}

// Round 4
// 498.398 us; speedup vs baseline: 4.1657x; 1.4952x over previous
//
#include <hip/hip_runtime.h>
#include <hip/hip_bf16.h>

// B=2, S=1024, L=1024, DIM_Q=2048, H=16, K=128, D_C=512, D_CQ=1536, R=64

typedef __attribute__((ext_vector_type(8))) short short8;
typedef __attribute__((ext_vector_type(4))) float f32x4;

__device__ __forceinline__ unsigned short f2bs(float v){
  __hip_bfloat16 b = __float2bfloat16(v);
  return *reinterpret_cast<unsigned short*>(&b);
}
__device__ __forceinline__ void storeC(float* p, float v){ *p = v; }
__device__ __forceinline__ void storeC(unsigned short* p, float v){ *p = f2bs(v); }

// async global->LDS, 16B per lane.  LDS dest = wave-uniform base + lane*16.
__device__ __forceinline__ void gl_lds16(const void* g, void* l){
  __builtin_amdgcn_global_load_lds(
      (const __attribute__((address_space(1))) unsigned int*)g,
      (__attribute__((address_space(3))) unsigned int*)l, 16, 0, 0);
}

// ---------------------------------------------------------------------------
__global__ __launch_bounds__(256) void build_tables(
    float* __restrict__ sinq, float* __restrict__ cosq,
    float* __restrict__ sink, float* __restrict__ cosk)
{
  int idx = blockIdx.x*256 + threadIdx.x;
  if (idx < 1024*768){
    int s = idx / 768, j = idx % 768;
    float f = (float)s * powf(10000.f, (-2.f*j)/1536.f);
    float sv = sinf(f), cv = cosf(f);
    int base = s*1536 + 2*j;
    sinq[base] = sv; sinq[base+1] = sv;
    cosq[base] = cv; cosq[base+1] = cv;
  } else {
    int k = idx - 1024*768;
    int l = k / 256, j = k % 256;
    float f = (float)l * powf(10000.f, (-2.f*j)/512.f);
    float sv = sinf(f), cv = cosf(f);
    int base = l*512 + 2*j;
    sink[base] = sv; sink[base+1] = sv;
    cosk[base] = cv; cosk[base+1] = cv;
  }
}

// ---------------------------------------------------------------------------
__global__ __launch_bounds__(256) void cvt_bf16(
    const float* __restrict__ in, unsigned short* __restrict__ out, int n4)
{
  int i = blockIdx.x*256 + threadIdx.x;
  if (i < n4){
    float4 v = *(const float4*)(in + (long)i*4);
    ushort4 u; u.x=f2bs(v.x); u.y=f2bs(v.y); u.z=f2bs(v.z); u.w=f2bs(v.w);
    *(ushort4*)(out + (long)i*4) = u;
  }
}

// fp32 [R,Cn] -> bf16 [Cn,R] per batch (32x32 LDS tiles)
__global__ __launch_bounds__(256) void transpose_cvt(
    const float* __restrict__ in, unsigned short* __restrict__ out,
    int R, int Cn, long sIn, long sOut)
{
  __shared__ float tile[32][33];
  const float* ip = in + (long)blockIdx.z*sIn;
  unsigned short* op = out + (long)blockIdx.z*sOut;
  int c0 = blockIdx.x*32, r0 = blockIdx.y*32;
  int tr = threadIdx.x>>5, tc = threadIdx.x&31;
  #pragma unroll
  for (int i=0;i<4;i++)
    tile[tr+i*8][tc] = ip[(long)(r0+tr+i*8)*Cn + c0+tc];
  __syncthreads();
  #pragma unroll
  for (int i=0;i<4;i++)
    op[(long)(c0+tr+i*8)*R + r0+tc] = f2bs(tile[tc][tr+i*8]);
}

// ---------------------------------------------------------------------------
// bf16 MFMA GEMM (NT): C[m,n] = sum_k A[m,k]*B[n,k], A/B bf16, C float or bf16.
template<int BM,int BN,int WM,int WN,typename TC>
__global__ __launch_bounds__(256) void gemm_mfma(
    const unsigned short* __restrict__ A, const unsigned short* __restrict__ B,
    TC* __restrict__ C,
    int Kd, int lda, int ldb, int ldc, int Hb,
    long sAb, long sAh, long sBb, long sBh, long sCb, long sCh)
{
  constexpr int MF = WM/16, NF = WN/16;
  constexpr int WGM = BM/WM;
  constexpr int AOPS = (4*BM)/256;
  constexpr int BOPS = (4*BN)/256;

  const int z = blockIdx.z, bb = z/Hb, hh = z - bb*Hb;
  const unsigned short* Ap = A + bb*sAb + hh*sAh;
  const unsigned short* Bp = B + bb*sBb + hh*sBh;
  TC* Cp = C + bb*sCb + hh*sCh;
  const int m0 = blockIdx.x*BM, n0 = blockIdx.y*BN;
  const int t = threadIdx.x, w = t>>6, l = t&63;
  const int wm0 = (w % WGM)*WM, wn0 = (w / WGM)*WN;
  const int lq = l>>4, lm = l&15;

  __shared__ __align__(16) unsigned short As[4*BM*8];
  __shared__ __align__(16) unsigned short Bs[4*BN*8];

  f32x4 acc[MF][NF];
  #pragma unroll
  for (int mf=0; mf<MF; ++mf)
    #pragma unroll
    for (int nf=0; nf<NF; ++nf)
      acc[mf][nf] = f32x4{0.f,0.f,0.f,0.f};

  for (int k0 = 0; k0 < Kd; k0 += 32){
    #pragma unroll
    for (int o = 0; o < AOPS; ++o){
      int g = o*256 + t;
      int row = g & (BM-1), kq = g / BM;
      gl_lds16(Ap + (long)(m0+row)*lda + k0 + kq*8, &As[(o*256 + w*64)*8]);
    }
    #pragma unroll
    for (int o = 0; o < BOPS; ++o){
      int g = o*256 + t;
      int row = g & (BN-1), kq = g / BN;
      gl_lds16(Bp + (long)(n0+row)*ldb + k0 + kq*8, &Bs[(o*256 + w*64)*8]);
    }
    __syncthreads();
    short8 af[MF], bfr[NF];
    #pragma unroll
    for (int mf=0; mf<MF; ++mf)
      af[mf] = *(const short8*)&As[(lq*BM + wm0 + mf*16 + lm)*8];
    #pragma unroll
    for (int nf=0; nf<NF; ++nf)
      bfr[nf] = *(const short8*)&Bs[(lq*BN + wn0 + nf*16 + lm)*8];
    #pragma unroll
    for (int mf=0; mf<MF; ++mf)
      #pragma unroll
      for (int nf=0; nf<NF; ++nf)
        acc[mf][nf] = __builtin_amdgcn_mfma_f32_16x16x32_bf16(
            af[mf], bfr[nf], acc[mf][nf], 0, 0, 0);
    __syncthreads();
  }

  #pragma unroll
  for (int mf=0; mf<MF; ++mf){
    #pragma unroll
    for (int nf=0; nf<NF; ++nf){
      int row = m0 + wm0 + mf*16 + lq*4;
      int col = n0 + wn0 + nf*16 + lm;
      #pragma unroll
      for (int r=0; r<4; ++r)
        storeC(&Cp[(long)(row+r)*ldc + col], acc[mf][nf][r]);
    }
  }
}

// ---------------------------------------------------------------------------
// RoPE on q_big (bf16, in place).  Layout [b,s][h*1536+q]; pairs (q, q+768).
__global__ __launch_bounds__(256) void rope_q_kernel(
    unsigned short* __restrict__ qb,
    const float* __restrict__ sq, const float* __restrict__ cq)
{
  int idx = blockIdx.x*256 + threadIdx.x;
  int row = idx / 768;
  int q = idx - row*768;
  int s = (row >> 4) & 1023;
  long base = (long)row*1536;
  float xl = __uint_as_float((unsigned)qb[base+q] << 16);
  float xh = __uint_as_float((unsigned)qb[base+q+768] << 16);
  int tb = s*1536 + q;
  float yl = xl*cq[tb]     - xh*sq[tb];
  float yh = xh*cq[tb+768] + xl*sq[tb+768];
  qb[base+q]     = f2bs(yl);
  qb[base+q+768] = f2bs(yh);
}

// RoPE on kv_c -> kv_rb bf16.  [b,l,512]; pairs (d, d+256).
__global__ __launch_bounds__(256) void rope_k_kernel(
    const float* __restrict__ kc,
    const float* __restrict__ sk, const float* __restrict__ ck,
    unsigned short* __restrict__ kvrb)
{
  int idx = blockIdx.x*256 + threadIdx.x;
  int row = idx >> 8;
  int d = idx & 255;
  int l = row & 1023;
  long base = (long)row*512;
  float xl = kc[base+d], xh = kc[base+d+256];
  int tb = l*512 + d;
  kvrb[base+d]     = f2bs(xl*ck[tb]     - xh*sk[tb]);
  kvrb[base+d+256] = f2bs(xh*ck[tb+256] + xl*sk[tb+256]);
}

// ---------------------------------------------------------------------------
// MFMA flash attention.  WG = (b, h, 64 q-rows); wave w owns q rows w*16..+15.
// q_r/k_r: [b,h][1024][64] bf16.  vt: V'^T [b,h][128][1024] bf16.
// Online softmax state in registers, replicated across 16-lane groups.
// P round-trips through LDS (C-layout -> A-layout), row stride 72 shorts
// (144 B, 16-aligned, 2-way banks = free).
__global__ __launch_bounds__(256) void flash_mfma(
    const unsigned short* __restrict__ qr, const unsigned short* __restrict__ kr,
    const unsigned short* __restrict__ vt, unsigned short* __restrict__ ctx)
{
  const int b = blockIdx.z, h = blockIdx.y, s0 = blockIdx.x*64;
  const int t = threadIdx.x, w = t>>6, l = t&63;
  const int lq = l>>4, lm = l&15;

  __shared__ __align__(16) unsigned short Qs[8*64*8];    // [kq][qrow][8]
  __shared__ __align__(16) unsigned short Ks[8*64*8];    // [kq][lrow][8]
  __shared__ __align__(16) unsigned short Vts[8*128*8];  // [kq][drow][8]
  __shared__ __align__(16) unsigned short Ps[64*72];     // [qrow][72]

  const unsigned short* qbase = qr + ((long)(b*16+h)*1024 + s0)*64;
  const unsigned short* kbase = kr + (long)(b*16+h)*65536;
  const unsigned short* vbase = vt + (long)(b*16+h)*131072;

  // stage Q once: rows = q (64), kq over r
  #pragma unroll
  for (int o = 0; o < 2; ++o){
    int g = o*256 + t;
    int row = g & 63, kq = g >> 6;
    gl_lds16(qbase + (long)row*64 + kq*8, &Qs[(o*256 + w*64)*8]);
  }
  __syncthreads();
  short8 aq[2];
  #pragma unroll
  for (int ks = 0; ks < 2; ++ks)
    aq[ks] = *(const short8*)&Qs[((ks*4+lq)*64 + w*16 + lm)*8];

  float m_run[4], l_run[4];
  #pragma unroll
  for (int r = 0; r < 4; ++r){ m_run[r] = -3e38f; l_run[r] = 0.f; }
  f32x4 acc_o[8];
  #pragma unroll
  for (int nf = 0; nf < 8; ++nf) acc_o[nf] = f32x4{0.f,0.f,0.f,0.f};

  for (int l0 = 0; l0 < 1024; l0 += 64){
    __syncthreads();
    // stage K tile: [kq(r)][l-row][8]
    #pragma unroll
    for (int o = 0; o < 2; ++o){
      int g = o*256 + t;
      int row = g & 63, kq = g >> 6;
      gl_lds16(kbase + (long)(l0+row)*64 + kq*8, &Ks[(o*256 + w*64)*8]);
    }
    // stage V'^T tile: [kq(l)][d-row][8]
    #pragma unroll
    for (int o = 0; o < 4; ++o){
      int g = o*256 + t;
      int row = g & 127, kq = g >> 7;
      gl_lds16(vbase + (long)row*1024 + l0 + kq*8, &Vts[(o*256 + w*64)*8]);
    }
    __syncthreads();

    // QK^T: S[16 q][64 l] per wave
    f32x4 acc_s[4];
    #pragma unroll
    for (int nf = 0; nf < 4; ++nf) acc_s[nf] = f32x4{0.f,0.f,0.f,0.f};
    #pragma unroll
    for (int ks = 0; ks < 2; ++ks)
      #pragma unroll
      for (int nf = 0; nf < 4; ++nf){
        short8 bf = *(const short8*)&Ks[((ks*4+lq)*64 + nf*16 + lm)*8];
        acc_s[nf] = __builtin_amdgcn_mfma_f32_16x16x32_bf16(
            aq[ks], bf, acc_s[nf], 0, 0, 0);
      }

    // online softmax (C layout: row=lq*4+r, col=nf*16+lm)
    float tmax[4];
    #pragma unroll
    for (int r = 0; r < 4; ++r)
      tmax[r] = fmaxf(fmaxf(acc_s[0][r], acc_s[1][r]),
                      fmaxf(acc_s[2][r], acc_s[3][r]));
    #pragma unroll
    for (int mask = 1; mask < 16; mask <<= 1)
      #pragma unroll
      for (int r = 0; r < 4; ++r)
        tmax[r] = fmaxf(tmax[r], __shfl_xor(tmax[r], mask));
    float alpha[4], rsum[4];
    #pragma unroll
    for (int r = 0; r < 4; ++r){
      float mnew = fmaxf(m_run[r], tmax[r]);
      alpha[r] = __expf(m_run[r] - mnew);
      m_run[r] = mnew;
      rsum[r] = 0.f;
    }
    #pragma unroll
    for (int nf = 0; nf < 4; ++nf)
      #pragma unroll
      for (int r = 0; r < 4; ++r){
        float p = __expf(acc_s[nf][r] - m_run[r]);
        rsum[r] += p;
        Ps[(w*16 + lq*4 + r)*72 + nf*16 + lm] = f2bs(p);
      }
    #pragma unroll
    for (int mask = 1; mask < 16; mask <<= 1)
      #pragma unroll
      for (int r = 0; r < 4; ++r)
        rsum[r] += __shfl_xor(rsum[r], mask);
    #pragma unroll
    for (int r = 0; r < 4; ++r)
      l_run[r] = l_run[r]*alpha[r] + rsum[r];

    // rescale O accum
    #pragma unroll
    for (int nf = 0; nf < 8; ++nf)
      #pragma unroll
      for (int r = 0; r < 4; ++r)
        acc_o[nf][r] *= alpha[r];

    // PV: A = P (own rows, via LDS), B = V'^T tile
    short8 ap[2];
    #pragma unroll
    for (int ks = 0; ks < 2; ++ks)
      ap[ks] = *(const short8*)&Ps[(w*16 + lm)*72 + ks*32 + lq*8];
    #pragma unroll
    for (int ks = 0; ks < 2; ++ks)
      #pragma unroll
      for (int nf = 0; nf < 8; ++nf){
        short8 bv = *(const short8*)&Vts[((ks*4+lq)*128 + nf*16 + lm)*8];
        acc_o[nf] = __builtin_amdgcn_mfma_f32_16x16x32_bf16(
            ap[ks], bv, acc_o[nf], 0, 0, 0);
      }
  }

  float inv[4];
  #pragma unroll
  for (int r = 0; r < 4; ++r) inv[r] = 1.f / l_run[r];
  #pragma unroll
  for (int nf = 0; nf < 8; ++nf)
    #pragma unroll
    for (int r = 0; r < 4; ++r){
      long row = (long)b*1024 + s0 + w*16 + lq*4 + r;
      ctx[row*2048 + h*128 + nf*16 + lm] = f2bs(acc_o[nf][r]*inv[r]);
    }
}

// ---------------------------------------------------------------------------
extern "C" void kernel_launch(void* const* d_in, const int* in_sizes, int n_in,
                              void* d_out, int out_size, void* d_ws, size_t ws_size,
                              hipStream_t stream)
{
  const float* hidden_q = (const float*)d_in[0];   // [2,1024,2048]
  const float* kv_c     = (const float*)d_in[1];   // [2,1024,512]
  const float* Wq       = (const float*)d_in[2];   // [2048,2048]
  const float* w_kc_q   = (const float*)d_in[3];   // [16,128,1536]
  const float* w_kc_kv  = (const float*)d_in[4];   // [16,128,512]
  const float* W_qr     = (const float*)d_in[5];   // [16,1536,64]
  const float* W_kr     = (const float*)d_in[6];   // [16,512,64]
  const float* Wo       = (const float*)d_in[7];   // [2048,2048]
  float* out = (float*)d_out;

  char* wsb = (char*)d_ws;
  size_t off = 0;
  auto take = [&](size_t bytes)->void*{
    void* p = wsb + off; off += (bytes + 255) & ~(size_t)255; return p;
  };
  unsigned short* q_rb  = (unsigned short*)take(4194304);  // [B,H,S,64] bf16
  unsigned short* k_rb  = (unsigned short*)take(4194304);  // [B,H,L,64] bf16
  unsigned short* kv_rb = (unsigned short*)take(2097152);  // [B,L,512] bf16
  float* sink   = (float*)take(2097152);
  float* cosk   = (float*)take(2097152);
  float* sinq   = (float*)take(6291456);
  float* cosq   = (float*)take(6291456);
  unsigned short* q_hk   = (unsigned short*)take(8388608); // [B*S,2048] bf16
  unsigned short* wkcqT  = (unsigned short*)take(6291456); // [16][1536][128] bf16
  unsigned short* WqrT   = (unsigned short*)take(3145728); // [16][64][1536] bf16
  unsigned short* wkckvb = (unsigned short*)take(2097152); // [16][128][512] bf16
  unsigned short* WkrT   = (unsigned short*)take(1048576); // [16][64][512] bf16
  unsigned short* Vt     = (unsigned short*)take(8388608); // [B,H,128,1024] bf16
  char* bigr = (char*)take(100663296);                     // 96 MiB shared region
  unsigned short* hiddenb = (unsigned short*)bigr;              // 8MB (dead after step2)
  unsigned short* Wqb     = (unsigned short*)(bigr + 8388608);  // 8MB (dead after step2)
  unsigned short* q_big   = (unsigned short*)bigr;              // 96MB (steps 3..5)
  unsigned short* Wob     = (unsigned short*)bigr;              // 8MB (after step5)
  unsigned short* ctx_lat = (unsigned short*)(bigr + 8388608);  // 8MB (flash out)

  // tables + converts
  build_tables<<<4096, 256, 0, stream>>>(sinq, cosq, sink, cosk);
  cvt_bf16<<<4096, 256, 0, stream>>>(hidden_q, hiddenb, 1048576);
  cvt_bf16<<<4096, 256, 0, stream>>>(Wq, Wqb, 1048576);
  cvt_bf16<<<1024, 256, 0, stream>>>(w_kc_kv, wkckvb, 262144);
  transpose_cvt<<<dim3(48,4,16), 256, 0, stream>>>(w_kc_q, wkcqT, 128, 1536, 196608, 196608);
  transpose_cvt<<<dim3(2,48,16), 256, 0, stream>>>(W_qr, WqrT, 1536, 64, 98304, 98304);
  transpose_cvt<<<dim3(2,16,16), 256, 0, stream>>>(W_kr, WkrT, 512, 64, 32768, 32768);

  // 2) q_hk = hidden @ Wq^T   (2048x2048x2048) -> bf16
  gemm_mfma<128,128,64,64,unsigned short><<<dim3(16,16,1),256,0,stream>>>(
      hiddenb, Wqb, q_hk, 2048, 2048,2048,2048, 1, 0,0, 0,0, 0,0);

  // 3) q_big = q_hk @ w_kc_q_T  (per (b,h): 1024x1536x128) -> bf16
  gemm_mfma<128,128,64,64,unsigned short><<<dim3(8,12,32),256,0,stream>>>(
      q_hk, wkcqT, q_big, 128, 2048,128,24576, 16,
      2097152,128, 0,196608, 25165824,1536);

  // 4) RoPE q_big in place
  rope_q_kernel<<<98304, 256, 0, stream>>>(q_big, sinq, cosq);

  // 5) q_r = q_big @ W_qr_T  (per (b,h): 1024x64x1536) -> bf16
  gemm_mfma<128,64,32,64,unsigned short><<<dim3(8,1,32),256,0,stream>>>(
      q_big, WqrT, q_rb, 1536, 24576,1536,64, 16,
      25165824,1536, 0,98304, 1048576,65536);

  // Wo convert (aliases dead q_big region — after step 5)
  cvt_bf16<<<4096, 256, 0, stream>>>(Wo, Wob, 1048576);

  // 6) kv_rb = RoPE(kv_c) bf16
  rope_k_kernel<<<2048, 256, 0, stream>>>(kv_c, sink, cosk, kv_rb);

  // 7) k_r = kv_rb @ W_kr_T  (per (b,h): 1024x64x512) -> bf16
  gemm_mfma<128,64,32,64,unsigned short><<<dim3(8,1,32),256,0,stream>>>(
      kv_rb, WkrT, k_rb, 512, 512,512,64, 16,
      524288,0, 0,32768, 1048576,65536);

  // 7b) V'^T[b,h][d][l] = w_kc_kv[h] @ kv_rb[b]^T  (per (b,h): 128x1024x512) -> bf16
  gemm_mfma<128,128,64,64,unsigned short><<<dim3(1,8,32),256,0,stream>>>(
      wkckvb, kv_rb, Vt, 512, 512,512,1024, 16,
      0,65536, 524288,0, 2097152,131072);

  // 8) MFMA flash attention -> ctx_lat bf16 [b,s][h*128+k]
  flash_mfma<<<dim3(16,16,2),256,0,stream>>>(q_rb, k_rb, Vt, ctx_lat);

  // 10) out = ctx_lat @ Wo^T  (2048x2048x2048) -> fp32
  gemm_mfma<128,128,64,64,float><<<dim3(16,16,1),256,0,stream>>>(
      ctx_lat, Wob, out, 2048, 2048,2048,2048, 1, 0,0, 0,0, 0,0);
}

// Round 5
// 464.589 us; speedup vs baseline: 4.4689x; 1.0728x over previous
//
#include <hip/hip_runtime.h>
#include <hip/hip_bf16.h>

// B=2, S=1024, L=1024, DIM_Q=2048, H=16, K=128, D_C=512, D_CQ=1536, R=64

typedef __attribute__((ext_vector_type(8))) short short8;
typedef __attribute__((ext_vector_type(4))) float f32x4;

__device__ __forceinline__ unsigned short f2bs(float v){
  __hip_bfloat16 b = __float2bfloat16(v);
  return *reinterpret_cast<unsigned short*>(&b);
}
__device__ __forceinline__ void storeC(float* p, float v){ *p = v; }
__device__ __forceinline__ void storeC(unsigned short* p, float v){ *p = f2bs(v); }

// async global->LDS, 16B per lane.  LDS dest = wave-uniform base + lane*16.
__device__ __forceinline__ void gl_lds16(const void* g, void* l){
  __builtin_amdgcn_global_load_lds(
      (const __attribute__((address_space(1))) unsigned int*)g,
      (__attribute__((address_space(3))) unsigned int*)l, 16, 0, 0);
}

// ---------------------------------------------------------------------------
__global__ __launch_bounds__(256) void build_tables(
    float* __restrict__ sinq, float* __restrict__ cosq,
    float* __restrict__ sink, float* __restrict__ cosk)
{
  int idx = blockIdx.x*256 + threadIdx.x;
  if (idx < 1024*768){
    int s = idx / 768, j = idx % 768;
    float f = (float)s * powf(10000.f, (-2.f*j)/1536.f);
    float sv = sinf(f), cv = cosf(f);
    int base = s*1536 + 2*j;
    sinq[base] = sv; sinq[base+1] = sv;
    cosq[base] = cv; cosq[base+1] = cv;
  } else {
    int k = idx - 1024*768;
    int l = k / 256, j = k % 256;
    float f = (float)l * powf(10000.f, (-2.f*j)/512.f);
    float sv = sinf(f), cv = cosf(f);
    int base = l*512 + 2*j;
    sink[base] = sv; sink[base+1] = sv;
    cosk[base] = cv; cosk[base+1] = cv;
  }
}

// ---------------------------------------------------------------------------
__global__ __launch_bounds__(256) void cvt_bf16(
    const float* __restrict__ in, unsigned short* __restrict__ out, int n4)
{
  int i = blockIdx.x*256 + threadIdx.x;
  if (i < n4){
    float4 v = *(const float4*)(in + (long)i*4);
    ushort4 u; u.x=f2bs(v.x); u.y=f2bs(v.y); u.z=f2bs(v.z); u.w=f2bs(v.w);
    *(ushort4*)(out + (long)i*4) = u;
  }
}

// fp32 [R,Cn] -> bf16 [Cn,R] per batch (32x32 LDS tiles)
__global__ __launch_bounds__(256) void transpose_cvt(
    const float* __restrict__ in, unsigned short* __restrict__ out,
    int R, int Cn, long sIn, long sOut)
{
  __shared__ float tile[32][33];
  const float* ip = in + (long)blockIdx.z*sIn;
  unsigned short* op = out + (long)blockIdx.z*sOut;
  int c0 = blockIdx.x*32, r0 = blockIdx.y*32;
  int tr = threadIdx.x>>5, tc = threadIdx.x&31;
  #pragma unroll
  for (int i=0;i<4;i++)
    tile[tr+i*8][tc] = ip[(long)(r0+tr+i*8)*Cn + c0+tc];
  __syncthreads();
  #pragma unroll
  for (int i=0;i<4;i++)
    op[(long)(c0+tr+i*8)*R + r0+tc] = f2bs(tile[tc][tr+i*8]);
}

// ---------------------------------------------------------------------------
// bf16 MFMA GEMM (NT): C[m,n] = sum_k A[m,k]*B[n,k], A/B bf16, C float or bf16.
// Tile BM x BN x 32; 256 threads = 4 waves; wave grid (BM/WM)x(BN/WN).
template<int BM,int BN,int WM,int WN,typename TC>
__global__ __launch_bounds__(256) void gemm_mfma(
    const unsigned short* __restrict__ A, const unsigned short* __restrict__ B,
    TC* __restrict__ C,
    int Kd, int lda, int ldb, int ldc, int Hb,
    long sAb, long sAh, long sBb, long sBh, long sCb, long sCh)
{
  constexpr int MF = WM/16, NF = WN/16;
  constexpr int WGM = BM/WM;
  constexpr int AOPS = (4*BM)/256;
  constexpr int BOPS = (4*BN)/256;

  const int z = blockIdx.z, bb = z/Hb, hh = z - bb*Hb;
  const unsigned short* Ap = A + bb*sAb + hh*sAh;
  const unsigned short* Bp = B + bb*sBb + hh*sBh;
  TC* Cp = C + bb*sCb + hh*sCh;
  const int m0 = blockIdx.x*BM, n0 = blockIdx.y*BN;
  const int t = threadIdx.x, w = t>>6, l = t&63;
  const int wm0 = (w % WGM)*WM, wn0 = (w / WGM)*WN;
  const int lq = l>>4, lm = l&15;

  __shared__ __align__(16) unsigned short As[4*BM*8];
  __shared__ __align__(16) unsigned short Bs[4*BN*8];

  f32x4 acc[MF][NF];
  #pragma unroll
  for (int mf=0; mf<MF; ++mf)
    #pragma unroll
    for (int nf=0; nf<NF; ++nf)
      acc[mf][nf] = f32x4{0.f,0.f,0.f,0.f};

  for (int k0 = 0; k0 < Kd; k0 += 32){
    #pragma unroll
    for (int o = 0; o < AOPS; ++o){
      int g = o*256 + t;
      int row = g & (BM-1), kq = g / BM;
      gl_lds16(Ap + (long)(m0+row)*lda + k0 + kq*8, &As[(o*256 + w*64)*8]);
    }
    #pragma unroll
    for (int o = 0; o < BOPS; ++o){
      int g = o*256 + t;
      int row = g & (BN-1), kq = g / BN;
      gl_lds16(Bp + (long)(n0+row)*ldb + k0 + kq*8, &Bs[(o*256 + w*64)*8]);
    }
    __syncthreads();
    short8 af[MF], bfr[NF];
    #pragma unroll
    for (int mf=0; mf<MF; ++mf)
      af[mf] = *(const short8*)&As[(lq*BM + wm0 + mf*16 + lm)*8];
    #pragma unroll
    for (int nf=0; nf<NF; ++nf)
      bfr[nf] = *(const short8*)&Bs[(lq*BN + wn0 + nf*16 + lm)*8];
    #pragma unroll
    for (int mf=0; mf<MF; ++mf)
      #pragma unroll
      for (int nf=0; nf<NF; ++nf)
        acc[mf][nf] = __builtin_amdgcn_mfma_f32_16x16x32_bf16(
            af[mf], bfr[nf], acc[mf][nf], 0, 0, 0);
    __syncthreads();
  }

  #pragma unroll
  for (int mf=0; mf<MF; ++mf){
    #pragma unroll
    for (int nf=0; nf<NF; ++nf){
      int row = m0 + wm0 + mf*16 + lq*4;
      int col = n0 + wn0 + nf*16 + lm;
      #pragma unroll
      for (int r=0; r<4; ++r)
        storeC(&Cp[(long)(row+r)*ldc + col], acc[mf][nf][r]);
    }
  }
}

// ---------------------------------------------------------------------------
// RoPE on q_big (bf16, in place).  Layout [b,s][h*1536+q]; pairs (q, q+768).
__global__ __launch_bounds__(256) void rope_q_kernel(
    unsigned short* __restrict__ qb,
    const float* __restrict__ sq, const float* __restrict__ cq)
{
  int idx = blockIdx.x*256 + threadIdx.x;
  int row = idx / 768;
  int q = idx - row*768;
  int s = (row >> 4) & 1023;
  long base = (long)row*1536;
  float xl = __uint_as_float((unsigned)qb[base+q] << 16);
  float xh = __uint_as_float((unsigned)qb[base+q+768] << 16);
  int tb = s*1536 + q;
  float yl = xl*cq[tb]     - xh*sq[tb];
  float yh = xh*cq[tb+768] + xl*sq[tb+768];
  qb[base+q]     = f2bs(yl);
  qb[base+q+768] = f2bs(yh);
}

// RoPE on kv_c -> kv_rb bf16.  [b,l,512]; pairs (d, d+256).
__global__ __launch_bounds__(256) void rope_k_kernel(
    const float* __restrict__ kc,
    const float* __restrict__ sk, const float* __restrict__ ck,
    unsigned short* __restrict__ kvrb)
{
  int idx = blockIdx.x*256 + threadIdx.x;
  int row = idx >> 8;
  int d = idx & 255;
  int l = row & 1023;
  long base = (long)row*512;
  float xl = kc[base+d], xh = kc[base+d+256];
  int tb = l*512 + d;
  kvrb[base+d]     = f2bs(xl*ck[tb]     - xh*sk[tb]);
  kvrb[base+d+256] = f2bs(xh*ck[tb+256] + xl*sk[tb+256]);
}

// ---------------------------------------------------------------------------
// MFMA flash attention.  WG = (b, h, 64 q-rows); wave w owns q rows w*16..+15.
__global__ __launch_bounds__(256) void flash_mfma(
    const unsigned short* __restrict__ qr, const unsigned short* __restrict__ kr,
    const unsigned short* __restrict__ vt, unsigned short* __restrict__ ctx)
{
  const int b = blockIdx.z, h = blockIdx.y, s0 = blockIdx.x*64;
  const int t = threadIdx.x, w = t>>6, l = t&63;
  const int lq = l>>4, lm = l&15;

  __shared__ __align__(16) unsigned short Qs[8*64*8];    // [kq][qrow][8]
  __shared__ __align__(16) unsigned short Ks[8*64*8];    // [kq][lrow][8]
  __shared__ __align__(16) unsigned short Vts[8*128*8];  // [kq][drow][8]
  __shared__ __align__(16) unsigned short Ps[64*72];     // [qrow][72]

  const unsigned short* qbase = qr + ((long)(b*16+h)*1024 + s0)*64;
  const unsigned short* kbase = kr + (long)(b*16+h)*65536;
  const unsigned short* vbase = vt + (long)(b*16+h)*131072;

  #pragma unroll
  for (int o = 0; o < 2; ++o){
    int g = o*256 + t;
    int row = g & 63, kq = g >> 6;
    gl_lds16(qbase + (long)row*64 + kq*8, &Qs[(o*256 + w*64)*8]);
  }
  __syncthreads();
  short8 aq[2];
  #pragma unroll
  for (int ks = 0; ks < 2; ++ks)
    aq[ks] = *(const short8*)&Qs[((ks*4+lq)*64 + w*16 + lm)*8];

  float m_run[4], l_run[4];
  #pragma unroll
  for (int r = 0; r < 4; ++r){ m_run[r] = -3e38f; l_run[r] = 0.f; }
  f32x4 acc_o[8];
  #pragma unroll
  for (int nf = 0; nf < 8; ++nf) acc_o[nf] = f32x4{0.f,0.f,0.f,0.f};

  for (int l0 = 0; l0 < 1024; l0 += 64){
    __syncthreads();
    #pragma unroll
    for (int o = 0; o < 2; ++o){
      int g = o*256 + t;
      int row = g & 63, kq = g >> 6;
      gl_lds16(kbase + (long)(l0+row)*64 + kq*8, &Ks[(o*256 + w*64)*8]);
    }
    #pragma unroll
    for (int o = 0; o < 4; ++o){
      int g = o*256 + t;
      int row = g & 127, kq = g >> 7;
      gl_lds16(vbase + (long)row*1024 + l0 + kq*8, &Vts[(o*256 + w*64)*8]);
    }
    __syncthreads();

    f32x4 acc_s[4];
    #pragma unroll
    for (int nf = 0; nf < 4; ++nf) acc_s[nf] = f32x4{0.f,0.f,0.f,0.f};
    #pragma unroll
    for (int ks = 0; ks < 2; ++ks)
      #pragma unroll
      for (int nf = 0; nf < 4; ++nf){
        short8 bf = *(const short8*)&Ks[((ks*4+lq)*64 + nf*16 + lm)*8];
        acc_s[nf] = __builtin_amdgcn_mfma_f32_16x16x32_bf16(
            aq[ks], bf, acc_s[nf], 0, 0, 0);
      }

    float tmax[4];
    #pragma unroll
    for (int r = 0; r < 4; ++r)
      tmax[r] = fmaxf(fmaxf(acc_s[0][r], acc_s[1][r]),
                      fmaxf(acc_s[2][r], acc_s[3][r]));
    #pragma unroll
    for (int mask = 1; mask < 16; mask <<= 1)
      #pragma unroll
      for (int r = 0; r < 4; ++r)
        tmax[r] = fmaxf(tmax[r], __shfl_xor(tmax[r], mask));
    float alpha[4], rsum[4];
    #pragma unroll
    for (int r = 0; r < 4; ++r){
      float mnew = fmaxf(m_run[r], tmax[r]);
      alpha[r] = __expf(m_run[r] - mnew);
      m_run[r] = mnew;
      rsum[r] = 0.f;
    }
    #pragma unroll
    for (int nf = 0; nf < 4; ++nf)
      #pragma unroll
      for (int r = 0; r < 4; ++r){
        float p = __expf(acc_s[nf][r] - m_run[r]);
        rsum[r] += p;
        Ps[(w*16 + lq*4 + r)*72 + nf*16 + lm] = f2bs(p);
      }
    #pragma unroll
    for (int mask = 1; mask < 16; mask <<= 1)
      #pragma unroll
      for (int r = 0; r < 4; ++r)
        rsum[r] += __shfl_xor(rsum[r], mask);
    #pragma unroll
    for (int r = 0; r < 4; ++r)
      l_run[r] = l_run[r]*alpha[r] + rsum[r];

    #pragma unroll
    for (int nf = 0; nf < 8; ++nf)
      #pragma unroll
      for (int r = 0; r < 4; ++r)
        acc_o[nf][r] *= alpha[r];

    short8 ap[2];
    #pragma unroll
    for (int ks = 0; ks < 2; ++ks)
      ap[ks] = *(const short8*)&Ps[(w*16 + lm)*72 + ks*32 + lq*8];
    #pragma unroll
    for (int ks = 0; ks < 2; ++ks)
      #pragma unroll
      for (int nf = 0; nf < 8; ++nf){
        short8 bv = *(const short8*)&Vts[((ks*4+lq)*128 + nf*16 + lm)*8];
        acc_o[nf] = __builtin_amdgcn_mfma_f32_16x16x32_bf16(
            ap[ks], bv, acc_o[nf], 0, 0, 0);
      }
  }

  float inv[4];
  #pragma unroll
  for (int r = 0; r < 4; ++r) inv[r] = 1.f / l_run[r];
  #pragma unroll
  for (int nf = 0; nf < 8; ++nf)
    #pragma unroll
    for (int r = 0; r < 4; ++r){
      long row = (long)b*1024 + s0 + w*16 + lq*4 + r;
      ctx[row*2048 + h*128 + nf*16 + lm] = f2bs(acc_o[nf][r]*inv[r]);
    }
}

// ---------------------------------------------------------------------------
extern "C" void kernel_launch(void* const* d_in, const int* in_sizes, int n_in,
                              void* d_out, int out_size, void* d_ws, size_t ws_size,
                              hipStream_t stream)
{
  const float* hidden_q = (const float*)d_in[0];   // [2,1024,2048]
  const float* kv_c     = (const float*)d_in[1];   // [2,1024,512]
  const float* Wq       = (const float*)d_in[2];   // [2048,2048]
  const float* w_kc_q   = (const float*)d_in[3];   // [16,128,1536]
  const float* w_kc_kv  = (const float*)d_in[4];   // [16,128,512]
  const float* W_qr     = (const float*)d_in[5];   // [16,1536,64]
  const float* W_kr     = (const float*)d_in[6];   // [16,512,64]
  const float* Wo       = (const float*)d_in[7];   // [2048,2048]
  float* out = (float*)d_out;

  char* wsb = (char*)d_ws;
  size_t off = 0;
  auto take = [&](size_t bytes)->void*{
    void* p = wsb + off; off += (bytes + 255) & ~(size_t)255; return p;
  };
  unsigned short* q_rb  = (unsigned short*)take(4194304);  // [B,H,S,64] bf16
  unsigned short* k_rb  = (unsigned short*)take(4194304);  // [B,H,L,64] bf16
  unsigned short* kv_rb = (unsigned short*)take(2097152);  // [B,L,512] bf16
  float* sink   = (float*)take(2097152);
  float* cosk   = (float*)take(2097152);
  float* sinq   = (float*)take(6291456);
  float* cosq   = (float*)take(6291456);
  unsigned short* q_hk   = (unsigned short*)take(8388608); // [B*S,2048] bf16
  unsigned short* wkcqT  = (unsigned short*)take(6291456); // [16][1536][128] bf16
  unsigned short* WqrT   = (unsigned short*)take(3145728); // [16][64][1536] bf16
  unsigned short* wkckvb = (unsigned short*)take(2097152); // [16][128][512] bf16
  unsigned short* WkrT   = (unsigned short*)take(1048576); // [16][64][512] bf16
  unsigned short* Vt     = (unsigned short*)take(8388608); // [B,H,128,1024] bf16
  char* bigr = (char*)take(100663296);                     // 96 MiB shared region
  unsigned short* hiddenb = (unsigned short*)bigr;              // 8MB (dead after step2)
  unsigned short* Wqb     = (unsigned short*)(bigr + 8388608);  // 8MB (dead after step2)
  unsigned short* q_big   = (unsigned short*)bigr;              // 96MB (steps 3..5)
  unsigned short* Wob     = (unsigned short*)bigr;              // 8MB (after step5)
  unsigned short* ctx_lat = (unsigned short*)(bigr + 8388608);  // 8MB (flash out)

  // tables + converts
  build_tables<<<4096, 256, 0, stream>>>(sinq, cosq, sink, cosk);
  cvt_bf16<<<4096, 256, 0, stream>>>(hidden_q, hiddenb, 1048576);
  cvt_bf16<<<4096, 256, 0, stream>>>(Wq, Wqb, 1048576);
  cvt_bf16<<<1024, 256, 0, stream>>>(w_kc_kv, wkckvb, 262144);
  transpose_cvt<<<dim3(48,4,16), 256, 0, stream>>>(w_kc_q, wkcqT, 128, 1536, 196608, 196608);
  transpose_cvt<<<dim3(2,48,16), 256, 0, stream>>>(W_qr, WqrT, 1536, 64, 98304, 98304);
  transpose_cvt<<<dim3(2,16,16), 256, 0, stream>>>(W_kr, WkrT, 512, 64, 32768, 32768);

  // 2) q_hk = hidden @ Wq^T   (2048x2048x2048) -> bf16
  //    128x64 tile -> 512 blocks = 2 blocks/CU (barrier-drain overlap)
  gemm_mfma<128,64,64,32,unsigned short><<<dim3(16,32,1),256,0,stream>>>(
      hiddenb, Wqb, q_hk, 2048, 2048,2048,2048, 1, 0,0, 0,0, 0,0);

  // 3) q_big = q_hk @ w_kc_q_T  (per (b,h): 1024x1536x128) -> bf16 (3072 blocks)
  gemm_mfma<128,128,64,64,unsigned short><<<dim3(8,12,32),256,0,stream>>>(
      q_hk, wkcqT, q_big, 128, 2048,128,24576, 16,
      2097152,128, 0,196608, 25165824,1536);

  // 4) RoPE q_big in place
  rope_q_kernel<<<98304, 256, 0, stream>>>(q_big, sinq, cosq);

  // 5) q_r = q_big @ W_qr_T  (per (b,h): 1024x64x1536) -> bf16 (512 blocks)
  gemm_mfma<64,64,32,32,unsigned short><<<dim3(16,1,32),256,0,stream>>>(
      q_big, WqrT, q_rb, 1536, 24576,1536,64, 16,
      25165824,1536, 0,98304, 1048576,65536);

  // Wo convert (aliases dead q_big region — after step 5)
  cvt_bf16<<<4096, 256, 0, stream>>>(Wo, Wob, 1048576);

  // 6) kv_rb = RoPE(kv_c) bf16
  rope_k_kernel<<<2048, 256, 0, stream>>>(kv_c, sink, cosk, kv_rb);

  // 7) k_r = kv_rb @ W_kr_T  (per (b,h): 1024x64x512) -> bf16 (512 blocks)
  gemm_mfma<64,64,32,32,unsigned short><<<dim3(16,1,32),256,0,stream>>>(
      kv_rb, WkrT, k_rb, 512, 512,512,64, 16,
      524288,0, 0,32768, 1048576,65536);

  // 7b) V'^T[b,h][d][l] = w_kc_kv[h] @ kv_rb[b]^T  (per (b,h): 128x1024x512) -> bf16 (512 blocks)
  gemm_mfma<128,64,64,32,unsigned short><<<dim3(1,16,32),256,0,stream>>>(
      wkckvb, kv_rb, Vt, 512, 512,512,1024, 16,
      0,65536, 524288,0, 2097152,131072);

  // 8) MFMA flash attention -> ctx_lat bf16 [b,s][h*128+k]
  flash_mfma<<<dim3(16,16,2),256,0,stream>>>(q_rb, k_rb, Vt, ctx_lat);

  // 10) out = ctx_lat @ Wo^T  (2048x2048x2048) -> fp32 (512 blocks)
  gemm_mfma<128,64,64,32,float><<<dim3(16,32,1),256,0,stream>>>(
      ctx_lat, Wob, out, 2048, 2048,2048,2048, 1, 0,0, 0,0, 0,0);
}

// Round 6
// 447.387 us; speedup vs baseline: 4.6407x; 1.0384x over previous
//
#include <hip/hip_runtime.h>
#include <hip/hip_bf16.h>

// B=2, S=1024, L=1024, DIM_Q=2048, H=16, K=128, D_C=512, D_CQ=1536, R=64

typedef __attribute__((ext_vector_type(8))) short short8;
typedef __attribute__((ext_vector_type(4))) float f32x4;

__device__ __forceinline__ unsigned short f2bs(float v){
  __hip_bfloat16 b = __float2bfloat16(v);
  return *reinterpret_cast<unsigned short*>(&b);
}
__device__ __forceinline__ void storeC(float* p, float v){ *p = v; }
__device__ __forceinline__ void storeC(unsigned short* p, float v){ *p = f2bs(v); }

// async global->LDS, 16B per lane.  LDS dest = wave-uniform base + lane*16.
__device__ __forceinline__ void gl_lds16(const void* g, void* l){
  __builtin_amdgcn_global_load_lds(
      (const __attribute__((address_space(1))) unsigned int*)g,
      (__attribute__((address_space(3))) unsigned int*)l, 16, 0, 0);
}

// ---------------------------------------------------------------------------
// prep_all: one launch for sin/cos tables + 3 fp32->bf16 converts.
// segments: [0,4096) tables | [4096,8192) hidden | [8192,12288) Wq |
//           [12288,13312) w_kc_kv
__global__ __launch_bounds__(256) void prep_all(
    float* __restrict__ sinq, float* __restrict__ cosq,
    float* __restrict__ sink, float* __restrict__ cosk,
    const float* __restrict__ hidden, unsigned short* __restrict__ hiddenb,
    const float* __restrict__ Wq, unsigned short* __restrict__ Wqb,
    const float* __restrict__ wkckv, unsigned short* __restrict__ wkckvb)
{
  int blk = blockIdx.x;
  if (blk < 4096){
    int idx = blk*256 + threadIdx.x;
    if (idx < 1024*768){
      int s = idx / 768, j = idx % 768;
      float f = (float)s * powf(10000.f, (-2.f*j)/1536.f);
      float sv = sinf(f), cv = cosf(f);
      int base = s*1536 + 2*j;
      sinq[base] = sv; sinq[base+1] = sv;
      cosq[base] = cv; cosq[base+1] = cv;
    } else {
      int k = idx - 1024*768;
      int l = k / 256, j = k % 256;
      float f = (float)l * powf(10000.f, (-2.f*j)/512.f);
      float sv = sinf(f), cv = cosf(f);
      int base = l*512 + 2*j;
      sink[base] = sv; sink[base+1] = sv;
      cosk[base] = cv; cosk[base+1] = cv;
    }
    return;
  }
  const float* in; unsigned short* out; int i;
  if (blk < 8192){ in = hidden; out = hiddenb; i = (blk-4096)*256 + threadIdx.x; }
  else if (blk < 12288){ in = Wq; out = Wqb; i = (blk-8192)*256 + threadIdx.x; }
  else { in = wkckv; out = wkckvb; i = (blk-12288)*256 + threadIdx.x; }
  float4 v = *(const float4*)(in + (long)i*4);
  ushort4 u; u.x=f2bs(v.x); u.y=f2bs(v.y); u.z=f2bs(v.z); u.w=f2bs(v.w);
  *(ushort4*)(out + (long)i*4) = u;
}

__global__ __launch_bounds__(256) void cvt_bf16(
    const float* __restrict__ in, unsigned short* __restrict__ out, int n4)
{
  int i = blockIdx.x*256 + threadIdx.x;
  if (i < n4){
    float4 v = *(const float4*)(in + (long)i*4);
    ushort4 u; u.x=f2bs(v.x); u.y=f2bs(v.y); u.z=f2bs(v.z); u.w=f2bs(v.w);
    *(ushort4*)(out + (long)i*4) = u;
  }
}

// fp32 [R,Cn] -> bf16 [Cn,R] per batch (32x32 LDS tiles)
__global__ __launch_bounds__(256) void transpose_cvt(
    const float* __restrict__ in, unsigned short* __restrict__ out,
    int R, int Cn, long sIn, long sOut)
{
  __shared__ float tile[32][33];
  const float* ip = in + (long)blockIdx.z*sIn;
  unsigned short* op = out + (long)blockIdx.z*sOut;
  int c0 = blockIdx.x*32, r0 = blockIdx.y*32;
  int tr = threadIdx.x>>5, tc = threadIdx.x&31;
  #pragma unroll
  for (int i=0;i<4;i++)
    tile[tr+i*8][tc] = ip[(long)(r0+tr+i*8)*Cn + c0+tc];
  __syncthreads();
  #pragma unroll
  for (int i=0;i<4;i++)
    op[(long)(c0+tr+i*8)*R + r0+tc] = f2bs(tile[tc][tr+i*8]);
}

// ---------------------------------------------------------------------------
// bf16 MFMA GEMM (NT), double-buffered LDS.  C[m,n] = sum_k A[m,k]*B[n,k].
// K-loop: barrier -> issue async loads for tile k+1 -> compute tile k.
// The loads age through a full compute phase before the next barrier's
// vmcnt(0) drain, hiding L2/L3 latency (the round-5 exposed stall).
template<int BM,int BN,int WM,int WN,typename TC>
__global__ __launch_bounds__(256) void gemm_mfma(
    const unsigned short* __restrict__ A, const unsigned short* __restrict__ B,
    TC* __restrict__ C,
    int Kd, int lda, int ldb, int ldc, int Hb,
    long sAb, long sAh, long sBb, long sBh, long sCb, long sCh)
{
  constexpr int MF = WM/16, NF = WN/16;
  constexpr int WGM = BM/WM;
  constexpr int AOPS = (4*BM)/256;
  constexpr int BOPS = (4*BN)/256;

  const int z = blockIdx.z, bb = z/Hb, hh = z - bb*Hb;
  const unsigned short* Ap = A + bb*sAb + hh*sAh;
  const unsigned short* Bp = B + bb*sBb + hh*sBh;
  TC* Cp = C + bb*sCb + hh*sCh;
  const int m0 = blockIdx.x*BM, n0 = blockIdx.y*BN;
  const int t = threadIdx.x, w = t>>6, l = t&63;
  const int wm0 = (w % WGM)*WM, wn0 = (w / WGM)*WN;
  const int lq = l>>4, lm = l&15;

  __shared__ __align__(16) unsigned short As[2][4*BM*8];
  __shared__ __align__(16) unsigned short Bs[2][4*BN*8];

  f32x4 acc[MF][NF];
  #pragma unroll
  for (int mf=0; mf<MF; ++mf)
    #pragma unroll
    for (int nf=0; nf<NF; ++nf)
      acc[mf][nf] = f32x4{0.f,0.f,0.f,0.f};

  auto stage = [&](int buf, int k0){
    #pragma unroll
    for (int o = 0; o < AOPS; ++o){
      int g = o*256 + t;
      int row = g & (BM-1), kq = g / BM;
      gl_lds16(Ap + (long)(m0+row)*lda + k0 + kq*8, &As[buf][(o*256 + w*64)*8]);
    }
    #pragma unroll
    for (int o = 0; o < BOPS; ++o){
      int g = o*256 + t;
      int row = g & (BN-1), kq = g / BN;
      gl_lds16(Bp + (long)(n0+row)*ldb + k0 + kq*8, &Bs[buf][(o*256 + w*64)*8]);
    }
  };

  stage(0, 0);
  const int nIter = Kd >> 5;
  for (int it = 0; it < nIter; ++it){
    const int cur = it & 1;
    __syncthreads();                      // drains stage(it) (aged 1 compute phase)
    if (it+1 < nIter) stage(cur^1, (it+1)*32);
    short8 af[MF], bfr[NF];
    #pragma unroll
    for (int mf=0; mf<MF; ++mf)
      af[mf] = *(const short8*)&As[cur][(lq*BM + wm0 + mf*16 + lm)*8];
    #pragma unroll
    for (int nf=0; nf<NF; ++nf)
      bfr[nf] = *(const short8*)&Bs[cur][(lq*BN + wn0 + nf*16 + lm)*8];
    #pragma unroll
    for (int mf=0; mf<MF; ++mf)
      #pragma unroll
      for (int nf=0; nf<NF; ++nf)
        acc[mf][nf] = __builtin_amdgcn_mfma_f32_16x16x32_bf16(
            af[mf], bfr[nf], acc[mf][nf], 0, 0, 0);
  }

  #pragma unroll
  for (int mf=0; mf<MF; ++mf){
    #pragma unroll
    for (int nf=0; nf<NF; ++nf){
      int row = m0 + wm0 + mf*16 + lq*4;
      int col = n0 + wn0 + nf*16 + lm;
      #pragma unroll
      for (int r=0; r<4; ++r)
        storeC(&Cp[(long)(row+r)*ldc + col], acc[mf][nf][r]);
    }
  }
}

// ---------------------------------------------------------------------------
// RoPE on q_big (bf16, in place).  Layout [b,s][h*1536+q]; pairs (q, q+768).
__global__ __launch_bounds__(256) void rope_q_kernel(
    unsigned short* __restrict__ qb,
    const float* __restrict__ sq, const float* __restrict__ cq)
{
  int idx = blockIdx.x*256 + threadIdx.x;
  int row = idx / 768;
  int q = idx - row*768;
  int s = (row >> 4) & 1023;
  long base = (long)row*1536;
  float xl = __uint_as_float((unsigned)qb[base+q] << 16);
  float xh = __uint_as_float((unsigned)qb[base+q+768] << 16);
  int tb = s*1536 + q;
  float yl = xl*cq[tb]     - xh*sq[tb];
  float yh = xh*cq[tb+768] + xl*sq[tb+768];
  qb[base+q]     = f2bs(yl);
  qb[base+q+768] = f2bs(yh);
}

// RoPE on kv_c -> kv_rb bf16.  [b,l,512]; pairs (d, d+256).
__global__ __launch_bounds__(256) void rope_k_kernel(
    const float* __restrict__ kc,
    const float* __restrict__ sk, const float* __restrict__ ck,
    unsigned short* __restrict__ kvrb)
{
  int idx = blockIdx.x*256 + threadIdx.x;
  int row = idx >> 8;
  int d = idx & 255;
  int l = row & 1023;
  long base = (long)row*512;
  float xl = kc[base+d], xh = kc[base+d+256];
  int tb = l*512 + d;
  kvrb[base+d]     = f2bs(xl*ck[tb]     - xh*sk[tb]);
  kvrb[base+d+256] = f2bs(xh*ck[tb+256] + xl*sk[tb+256]);
}

// ---------------------------------------------------------------------------
// MFMA flash attention, double-buffered K/V staging (one barrier per tile).
// WG = (b, h, 64 q-rows); wave w owns q rows w*16..+15.
__global__ __launch_bounds__(256) void flash_mfma(
    const unsigned short* __restrict__ qr, const unsigned short* __restrict__ kr,
    const unsigned short* __restrict__ vt, unsigned short* __restrict__ ctx)
{
  const int b = blockIdx.z, h = blockIdx.y, s0 = blockIdx.x*64;
  const int t = threadIdx.x, w = t>>6, l = t&63;
  const int lq = l>>4, lm = l&15;

  __shared__ __align__(16) unsigned short Qs[8*64*8];       // [kq][qrow][8]
  __shared__ __align__(16) unsigned short Ks[2][8*64*8];    // [kq][lrow][8]
  __shared__ __align__(16) unsigned short Vts[2][8*128*8];  // [kq][drow][8]
  __shared__ __align__(16) unsigned short Ps[64*72];        // [qrow][72]

  const unsigned short* qbase = qr + ((long)(b*16+h)*1024 + s0)*64;
  const unsigned short* kbase = kr + (long)(b*16+h)*65536;
  const unsigned short* vbase = vt + (long)(b*16+h)*131072;

  auto stageKV = [&](int buf, int l0){
    #pragma unroll
    for (int o = 0; o < 2; ++o){
      int g = o*256 + t;
      int row = g & 63, kq = g >> 6;
      gl_lds16(kbase + (long)(l0+row)*64 + kq*8, &Ks[buf][(o*256 + w*64)*8]);
    }
    #pragma unroll
    for (int o = 0; o < 4; ++o){
      int g = o*256 + t;
      int row = g & 127, kq = g >> 7;
      gl_lds16(vbase + (long)row*1024 + l0 + kq*8, &Vts[buf][(o*256 + w*64)*8]);
    }
  };

  // stage Q once + first K/V tile
  #pragma unroll
  for (int o = 0; o < 2; ++o){
    int g = o*256 + t;
    int row = g & 63, kq = g >> 6;
    gl_lds16(qbase + (long)row*64 + kq*8, &Qs[(o*256 + w*64)*8]);
  }
  stageKV(0, 0);
  __syncthreads();
  short8 aq[2];
  #pragma unroll
  for (int ks = 0; ks < 2; ++ks)
    aq[ks] = *(const short8*)&Qs[((ks*4+lq)*64 + w*16 + lm)*8];

  float m_run[4], l_run[4];
  #pragma unroll
  for (int r = 0; r < 4; ++r){ m_run[r] = -3e38f; l_run[r] = 0.f; }
  f32x4 acc_o[8];
  #pragma unroll
  for (int nf = 0; nf < 8; ++nf) acc_o[nf] = f32x4{0.f,0.f,0.f,0.f};

  for (int it = 0; it < 16; ++it){
    const int cur = it & 1;
    __syncthreads();                    // drains stage(it); compute(it-1) done
    if (it < 15) stageKV(cur^1, (it+1)*64);

    f32x4 acc_s[4];
    #pragma unroll
    for (int nf = 0; nf < 4; ++nf) acc_s[nf] = f32x4{0.f,0.f,0.f,0.f};
    #pragma unroll
    for (int ks = 0; ks < 2; ++ks)
      #pragma unroll
      for (int nf = 0; nf < 4; ++nf){
        short8 bf = *(const short8*)&Ks[cur][((ks*4+lq)*64 + nf*16 + lm)*8];
        acc_s[nf] = __builtin_amdgcn_mfma_f32_16x16x32_bf16(
            aq[ks], bf, acc_s[nf], 0, 0, 0);
      }

    float tmax[4];
    #pragma unroll
    for (int r = 0; r < 4; ++r)
      tmax[r] = fmaxf(fmaxf(acc_s[0][r], acc_s[1][r]),
                      fmaxf(acc_s[2][r], acc_s[3][r]));
    #pragma unroll
    for (int mask = 1; mask < 16; mask <<= 1)
      #pragma unroll
      for (int r = 0; r < 4; ++r)
        tmax[r] = fmaxf(tmax[r], __shfl_xor(tmax[r], mask));
    float alpha[4], rsum[4];
    #pragma unroll
    for (int r = 0; r < 4; ++r){
      float mnew = fmaxf(m_run[r], tmax[r]);
      alpha[r] = __expf(m_run[r] - mnew);
      m_run[r] = mnew;
      rsum[r] = 0.f;
    }
    #pragma unroll
    for (int nf = 0; nf < 4; ++nf)
      #pragma unroll
      for (int r = 0; r < 4; ++r){
        float p = __expf(acc_s[nf][r] - m_run[r]);
        rsum[r] += p;
        Ps[(w*16 + lq*4 + r)*72 + nf*16 + lm] = f2bs(p);
      }
    #pragma unroll
    for (int mask = 1; mask < 16; mask <<= 1)
      #pragma unroll
      for (int r = 0; r < 4; ++r)
        rsum[r] += __shfl_xor(rsum[r], mask);
    #pragma unroll
    for (int r = 0; r < 4; ++r)
      l_run[r] = l_run[r]*alpha[r] + rsum[r];

    #pragma unroll
    for (int nf = 0; nf < 8; ++nf)
      #pragma unroll
      for (int r = 0; r < 4; ++r)
        acc_o[nf][r] *= alpha[r];

    short8 ap[2];
    #pragma unroll
    for (int ks = 0; ks < 2; ++ks)
      ap[ks] = *(const short8*)&Ps[(w*16 + lm)*72 + ks*32 + lq*8];
    #pragma unroll
    for (int ks = 0; ks < 2; ++ks)
      #pragma unroll
      for (int nf = 0; nf < 8; ++nf){
        short8 bv = *(const short8*)&Vts[cur][((ks*4+lq)*128 + nf*16 + lm)*8];
        acc_o[nf] = __builtin_amdgcn_mfma_f32_16x16x32_bf16(
            ap[ks], bv, acc_o[nf], 0, 0, 0);
      }
  }

  float inv[4];
  #pragma unroll
  for (int r = 0; r < 4; ++r) inv[r] = 1.f / l_run[r];
  #pragma unroll
  for (int nf = 0; nf < 8; ++nf)
    #pragma unroll
    for (int r = 0; r < 4; ++r){
      long row = (long)b*1024 + s0 + w*16 + lq*4 + r;
      ctx[row*2048 + h*128 + nf*16 + lm] = f2bs(acc_o[nf][r]*inv[r]);
    }
}

// ---------------------------------------------------------------------------
extern "C" void kernel_launch(void* const* d_in, const int* in_sizes, int n_in,
                              void* d_out, int out_size, void* d_ws, size_t ws_size,
                              hipStream_t stream)
{
  const float* hidden_q = (const float*)d_in[0];   // [2,1024,2048]
  const float* kv_c     = (const float*)d_in[1];   // [2,1024,512]
  const float* Wq       = (const float*)d_in[2];   // [2048,2048]
  const float* w_kc_q   = (const float*)d_in[3];   // [16,128,1536]
  const float* w_kc_kv  = (const float*)d_in[4];   // [16,128,512]
  const float* W_qr     = (const float*)d_in[5];   // [16,1536,64]
  const float* W_kr     = (const float*)d_in[6];   // [16,512,64]
  const float* Wo       = (const float*)d_in[7];   // [2048,2048]
  float* out = (float*)d_out;

  char* wsb = (char*)d_ws;
  size_t off = 0;
  auto take = [&](size_t bytes)->void*{
    void* p = wsb + off; off += (bytes + 255) & ~(size_t)255; return p;
  };
  unsigned short* q_rb  = (unsigned short*)take(4194304);  // [B,H,S,64] bf16
  unsigned short* k_rb  = (unsigned short*)take(4194304);  // [B,H,L,64] bf16
  unsigned short* kv_rb = (unsigned short*)take(2097152);  // [B,L,512] bf16
  float* sink   = (float*)take(2097152);
  float* cosk   = (float*)take(2097152);
  float* sinq   = (float*)take(6291456);
  float* cosq   = (float*)take(6291456);
  unsigned short* q_hk   = (unsigned short*)take(8388608); // [B*S,2048] bf16
  unsigned short* wkcqT  = (unsigned short*)take(6291456); // [16][1536][128] bf16
  unsigned short* WqrT   = (unsigned short*)take(3145728); // [16][64][1536] bf16
  unsigned short* wkckvb = (unsigned short*)take(2097152); // [16][128][512] bf16
  unsigned short* WkrT   = (unsigned short*)take(1048576); // [16][64][512] bf16
  unsigned short* Vt     = (unsigned short*)take(8388608); // [B,H,128,1024] bf16
  char* bigr = (char*)take(100663296);                     // 96 MiB shared region
  unsigned short* hiddenb = (unsigned short*)bigr;              // 8MB (dead after step2)
  unsigned short* Wqb     = (unsigned short*)(bigr + 8388608);  // 8MB (dead after step2)
  unsigned short* q_big   = (unsigned short*)bigr;              // 96MB (steps 3..5)
  unsigned short* Wob     = (unsigned short*)bigr;              // 8MB (after step5)
  unsigned short* ctx_lat = (unsigned short*)(bigr + 8388608);  // 8MB (flash out)

  // tables + 3 converts in one launch
  prep_all<<<13312, 256, 0, stream>>>(sinq, cosq, sink, cosk,
      hidden_q, hiddenb, Wq, Wqb, w_kc_kv, wkckvb);
  transpose_cvt<<<dim3(48,4,16), 256, 0, stream>>>(w_kc_q, wkcqT, 128, 1536, 196608, 196608);
  transpose_cvt<<<dim3(2,48,16), 256, 0, stream>>>(W_qr, WqrT, 1536, 64, 98304, 98304);
  transpose_cvt<<<dim3(2,16,16), 256, 0, stream>>>(W_kr, WkrT, 512, 64, 32768, 32768);

  // 2) q_hk = hidden @ Wq^T   (2048x2048x2048) -> bf16  (512 blocks = 2/CU)
  gemm_mfma<128,64,64,32,unsigned short><<<dim3(16,32,1),256,0,stream>>>(
      hiddenb, Wqb, q_hk, 2048, 2048,2048,2048, 1, 0,0, 0,0, 0,0);

  // 3) q_big = q_hk @ w_kc_q_T  (per (b,h): 1024x1536x128) -> bf16 (3072 blocks)
  gemm_mfma<128,128,64,64,unsigned short><<<dim3(8,12,32),256,0,stream>>>(
      q_hk, wkcqT, q_big, 128, 2048,128,24576, 16,
      2097152,128, 0,196608, 25165824,1536);

  // 4) RoPE q_big in place
  rope_q_kernel<<<98304, 256, 0, stream>>>(q_big, sinq, cosq);

  // 5) q_r = q_big @ W_qr_T  (per (b,h): 1024x64x1536) -> bf16 (512 blocks)
  gemm_mfma<64,64,32,32,unsigned short><<<dim3(16,1,32),256,0,stream>>>(
      q_big, WqrT, q_rb, 1536, 24576,1536,64, 16,
      25165824,1536, 0,98304, 1048576,65536);

  // Wo convert (aliases dead q_big region — after step 5)
  cvt_bf16<<<4096, 256, 0, stream>>>(Wo, Wob, 1048576);

  // 6) kv_rb = RoPE(kv_c) bf16
  rope_k_kernel<<<2048, 256, 0, stream>>>(kv_c, sink, cosk, kv_rb);

  // 7) k_r = kv_rb @ W_kr_T  (per (b,h): 1024x64x512) -> bf16 (512 blocks)
  gemm_mfma<64,64,32,32,unsigned short><<<dim3(16,1,32),256,0,stream>>>(
      kv_rb, WkrT, k_rb, 512, 512,512,64, 16,
      524288,0, 0,32768, 1048576,65536);

  // 7b) V'^T[b,h][d][l] = w_kc_kv[h] @ kv_rb[b]^T  (per (b,h): 128x1024x512) -> bf16 (512 blocks)
  gemm_mfma<128,64,64,32,unsigned short><<<dim3(1,16,32),256,0,stream>>>(
      wkckvb, kv_rb, Vt, 512, 512,512,1024, 16,
      0,65536, 524288,0, 2097152,131072);

  // 8) MFMA flash attention -> ctx_lat bf16 [b,s][h*128+k]
  flash_mfma<<<dim3(16,16,2),256,0,stream>>>(q_rb, k_rb, Vt, ctx_lat);

  // 10) out = ctx_lat @ Wo^T  (2048x2048x2048) -> fp32 (512 blocks)
  gemm_mfma<128,64,64,32,float><<<dim3(16,32,1),256,0,stream>>>(
      ctx_lat, Wob, out, 2048, 2048,2048,2048, 1, 0,0, 0,0, 0,0);
}